// Round 3
// baseline (245.878 us; speedup 1.0000x reference)
//
#include <hip/hip_runtime.h>
#include <math.h>

// Problem constants (fixed by setup_inputs)
#define NP 8192      // pred vertices
#define NG 12000     // gt vertices
#define NFP 16384    // pred faces
#define NFG 24000    // gt faces
#define EPSF 1e-6f

// uniform grid for NN: 16^3 cells over [0,1]^3, ~3 gt / ~2 pred per cell
#define GR 16
#define NC (GR*GR*GR)        // 4096
#define HCELL 0.0625f        // 1/16, exact power of two

// Dispatch 1: 9 blocks x 1024 thr, 144000 B dynamic LDS
//   b0: pred grid build   b1: gt grid build   b2: zero accum/done
//   b3..6: pred-face quadrants (range-half x face-half) -> pnn/nsum/deg A|B
//   b7..8: gt-face halves -> gtnA | gtnB
#define PF_R 4096            // pred-face vertex range per block (7*PF_R*4 = 114688 B)
#define D1_LDS_BYTES 144000  // gt-face needs NG*3 floats = 144000 B (max role)

// Dispatch 2: one lane per query, 256-thr blocks
#define PQ_BLOCKS (NP / 256)            // 32
#define GQ_BLOCKS ((NG + 255) / 256)    // 47 (last block 224 active)
#define D2_BLOCKS (PQ_BLOCKS + GQ_BLOCKS) // 79

// ---- workspace layout (bytes) ----
static constexpr size_t OFF_STARTP = 0;        // (NC+1) u32, [NC]=NP
static constexpr size_t OFF_STARTG = 16640;    // (NC+1) u32, [NC]=NG
static constexpr size_t OFF_SORTP  = 33280;    // 8192  float4 (x,y,z,idx-bits)
static constexpr size_t OFF_SORTG  = 164352;   // 12000 float4
static constexpr size_t OFF_PNNA   = 356352;   // NP*3 f32 (faces 0..8191)
static constexpr size_t OFF_PNNB   = 454656;   // NP*3 f32 (faces 8192..16383)
static constexpr size_t OFF_NSUMA  = 552960;   // NP*3 f32
static constexpr size_t OFF_NSUMB  = 651264;   // NP*3 f32
static constexpr size_t OFF_DEGA   = 749568;   // NP f32
static constexpr size_t OFF_DEGB   = 782336;   // NP f32
static constexpr size_t OFF_GTNA   = 815104;   // NG*3 f32 (faces 0..11999)
static constexpr size_t OFF_GTNB   = 959104;   // NG*3 f32 (faces 12000..23999)
static constexpr size_t OFF_ACCUM  = 1103104;  // 8 f32 global accumulators
static constexpr size_t OFF_DONE   = 1103136;  // 1 u32 done-counter

__device__ __forceinline__ int cell_of(float x) {
    int c = (int)(x * (float)GR);
    return min(max(c, 0), GR - 1);
}

// One block builds one point set: histogram -> shuffle scan -> start[] ->
// scatter into cell-sorted order via LDS cursor table.
__device__ __forceinline__ void build_cells(const float* __restrict__ pts, int n,
                                            unsigned* __restrict__ start,
                                            float4* __restrict__ sorted,
                                            unsigned* h, unsigned* wsum) {
    int t = threadIdx.x;                 // 0..1023
    int lane = t & 63, wid = t >> 6;     // 16 waves
    for (int i = t; i < NC; i += 1024) h[i] = 0u;
    __syncthreads();
    for (int i = t; i < n; i += 1024) {
        int c = (cell_of(pts[3*i+2]) * GR + cell_of(pts[3*i+1])) * GR + cell_of(pts[3*i]);
        atomicAdd(&h[c], 1u);
    }
    __syncthreads();
    unsigned a0 = h[4*t], a1 = h[4*t+1], a2 = h[4*t+2], a3 = h[4*t+3];
    unsigned tsum = a0 + a1 + a2 + a3;
    unsigned x = tsum;
    #pragma unroll
    for (int off = 1; off < 64; off <<= 1) {
        unsigned y = __shfl_up(x, off, 64);
        if (lane >= off) x += y;
    }
    if (lane == 63) wsum[wid] = x;       // wave totals
    __syncthreads();
    if (t < 16) {                        // scan 16 wave totals inside wave 0
        unsigned w = wsum[t];
        #pragma unroll
        for (int off = 1; off < 16; off <<= 1) {
            unsigned y = __shfl_up(w, off, 64);
            if (t >= off) w += y;
        }
        wsum[t] = w;                     // inclusive
    }
    __syncthreads();
    unsigned base = (wid ? wsum[wid-1] : 0u) + (x - tsum);  // exclusive prefix
    unsigned e0 = base, e1 = base + a0, e2 = base + a0 + a1, e3 = base + a0 + a1 + a2;
    start[4*t] = e0; start[4*t+1] = e1; start[4*t+2] = e2; start[4*t+3] = e3;
    h[4*t] = e0; h[4*t+1] = e1; h[4*t+2] = e2; h[4*t+3] = e3;  // reuse as cursor
    __syncthreads();
    for (int i = t; i < n; i += 1024) {
        float px = pts[3*i], py = pts[3*i+1], pz = pts[3*i+2];
        int c = (cell_of(pz) * GR + cell_of(py)) * GR + cell_of(px);
        unsigned pos = atomicAdd(&h[c], 1u);
        sorted[pos] = make_float4(px, py, pz, __int_as_float(i));
    }
    if (t == 0) start[NC] = (unsigned)n;   // end sentinel
}

// Dispatch 1. Face accumulation depends only on raw inputs -> runs here,
// concurrent with the 2 grid-build blocks (which otherwise leave the GPU
// idle). Big LDS is free: only 9 blocks, every block gets its own CU.
// Dual output buffers (A/B by face-half) -> plain stores, no zeroing pass,
// zero global float atomics anywhere.
__global__ __launch_bounds__(1024) void build_kernel(const float* __restrict__ pred,
                                                     const float* __restrict__ gt,
                                                     const int* __restrict__ pf,
                                                     const int* __restrict__ gf,
                                                     unsigned* __restrict__ startP,
                                                     unsigned* __restrict__ startG,
                                                     float4* __restrict__ sortP,
                                                     float4* __restrict__ sortG,
                                                     float* __restrict__ pnnA,
                                                     float* __restrict__ pnnB,
                                                     float* __restrict__ nsumA,
                                                     float* __restrict__ nsumB,
                                                     float* __restrict__ degA,
                                                     float* __restrict__ degB,
                                                     float* __restrict__ gtnA,
                                                     float* __restrict__ gtnB,
                                                     float* __restrict__ accum,
                                                     unsigned* __restrict__ done) {
    extern __shared__ float lds[];
    int b = blockIdx.x, t = threadIdx.x;
    if (b == 0) {
        build_cells(pred, NP, startP, sortP, (unsigned*)lds, (unsigned*)lds + NC);
    } else if (b == 1) {
        build_cells(gt, NG, startG, sortG, (unsigned*)lds, (unsigned*)lds + NC);
    } else if (b == 2) {
        if (t < 8) accum[t] = 0.0f;
        if (t == 8) *done = 0u;
    } else if (b <= 6) {
        // pred-face quadrant: q>>1 = range half, q&1 = face half (-> buffer A/B)
        int q = b - 3;
        int rb = (q >> 1) * PF_R;
        int f0 = (q & 1) * (NFP / 2);
        float* opnn  = (q & 1) ? pnnB  : pnnA;
        float* onsum = (q & 1) ? nsumB : nsumA;
        float* odeg  = (q & 1) ? degB  : degA;
        for (int i = t; i < 7 * PF_R; i += 1024) lds[i] = 0.0f;
        __syncthreads();
        for (int f = f0 + t; f < f0 + NFP / 2; f += 1024) {
            int i0 = pf[3*f], i1 = pf[3*f+1], i2 = pf[3*f+2];
            float ax = pred[3*i0], ay = pred[3*i0+1], az = pred[3*i0+2];
            float bx = pred[3*i1], by = pred[3*i1+1], bz = pred[3*i1+2];
            float cx = pred[3*i2], cy = pred[3*i2+1], cz = pred[3*i2+2];
            float ux = bx-ax, uy = by-ay, uz = bz-az;
            float wx = cx-ax, wy = cy-ay, wz = cz-az;
            float nx = uy*wz - uz*wy, ny = uz*wx - ux*wz, nz = ux*wy - uy*wx;
            if ((unsigned)(i0 - rb) < PF_R) {
                int l = i0 - rb;
                atomicAdd(&lds[3*l+0], nx); atomicAdd(&lds[3*l+1], ny); atomicAdd(&lds[3*l+2], nz);
                atomicAdd(&lds[3*PF_R+3*l+0], bx+cx); atomicAdd(&lds[3*PF_R+3*l+1], by+cy); atomicAdd(&lds[3*PF_R+3*l+2], bz+cz);
                atomicAdd(&lds[6*PF_R+l], 2.0f);
            }
            if ((unsigned)(i1 - rb) < PF_R) {
                int l = i1 - rb;
                atomicAdd(&lds[3*l+0], nx); atomicAdd(&lds[3*l+1], ny); atomicAdd(&lds[3*l+2], nz);
                atomicAdd(&lds[3*PF_R+3*l+0], cx+ax); atomicAdd(&lds[3*PF_R+3*l+1], cy+ay); atomicAdd(&lds[3*PF_R+3*l+2], cz+az);
                atomicAdd(&lds[6*PF_R+l], 2.0f);
            }
            if ((unsigned)(i2 - rb) < PF_R) {
                int l = i2 - rb;
                atomicAdd(&lds[3*l+0], nx); atomicAdd(&lds[3*l+1], ny); atomicAdd(&lds[3*l+2], nz);
                atomicAdd(&lds[3*PF_R+3*l+0], ax+bx); atomicAdd(&lds[3*PF_R+3*l+1], ay+by); atomicAdd(&lds[3*PF_R+3*l+2], az+bz);
                atomicAdd(&lds[6*PF_R+l], 2.0f);
            }
        }
        __syncthreads();
        for (int i = t; i < 3 * PF_R; i += 1024) {
            opnn[3*rb + i]  = lds[i];
            onsum[3*rb + i] = lds[3*PF_R + i];
        }
        for (int i = t; i < PF_R; i += 1024) odeg[rb + i] = lds[6*PF_R + i];
    } else {
        // gt-face half: full 12000-vertex range in LDS, own half of faces
        int hb = b - 7;
        int f0 = hb * (NFG / 2);
        float* og = hb ? gtnB : gtnA;
        for (int i = t; i < 3 * NG; i += 1024) lds[i] = 0.0f;
        __syncthreads();
        for (int f = f0 + t; f < f0 + NFG / 2; f += 1024) {
            int i0 = gf[3*f], i1 = gf[3*f+1], i2 = gf[3*f+2];
            float ax = gt[3*i0], ay = gt[3*i0+1], az = gt[3*i0+2];
            float bx = gt[3*i1], by = gt[3*i1+1], bz = gt[3*i1+2];
            float cx = gt[3*i2], cy = gt[3*i2+1], cz = gt[3*i2+2];
            float ux = bx-ax, uy = by-ay, uz = bz-az;
            float wx = cx-ax, wy = cy-ay, wz = cz-az;
            float nx = uy*wz - uz*wy, ny = uz*wx - ux*wz, nz = ux*wy - uy*wx;
            atomicAdd(&lds[3*i0+0], nx); atomicAdd(&lds[3*i0+1], ny); atomicAdd(&lds[3*i0+2], nz);
            atomicAdd(&lds[3*i1+0], nx); atomicAdd(&lds[3*i1+1], ny); atomicAdd(&lds[3*i1+2], nz);
            atomicAdd(&lds[3*i2+0], nx); atomicAdd(&lds[3*i2+1], ny); atomicAdd(&lds[3*i2+2], nz);
        }
        __syncthreads();
        for (int i = t; i < 3 * NG; i += 1024) og[i] = lds[i];
    }
}

__device__ __forceinline__ float wave_sum(float x) {
    #pragma unroll
    for (int o = 32; o > 0; o >>= 1) x += __shfl_down(x, o, 64);
    return x;
}

__device__ __forceinline__ unsigned long long u64min(unsigned long long a,
                                                     unsigned long long b) {
    return a < b ? a : b;
}

__device__ __forceinline__ unsigned long long pack_key(float px, float py, float pz,
                                                       float4 q) {
    float ddx = px - q.x, ddy = py - q.y, ddz = pz - q.z;
    float d2 = fmaf(ddx, ddx, fmaf(ddy, ddy, ddz*ddz));
    return ((unsigned long long)__float_as_uint(d2) << 32) |
           (unsigned)__float_as_int(q.w);
}

// One LANE per query (was 16 lanes/query): ~4 wave-inst per query instead of
// ~25, no cross-lane reduce, all point loads independent -> deep MLP.
// Adjacent lanes hold cell-sorted neighboring queries, so loop bounds stay
// convergent and loads are L1-hot. Expanding box, exact same termination
// rule as before (blo >= HCELL at r=1, so P(expand) ~1e-4).
__device__ __forceinline__ unsigned long long lane_nn(float px, float py, float pz,
                                                      const float4* __restrict__ S,
                                                      const unsigned* __restrict__ cstart) {
    int cx = cell_of(px), cy = cell_of(py), cz = cell_of(pz);
    unsigned long long best = 0xFFFFFFFFFFFFFFFFULL;
    for (int r = 1; ; ++r) {
        int x0 = max(cx - r, 0), x1 = min(cx + r, GR - 1);
        int y0 = max(cy - r, 0), y1 = min(cy + r, GR - 1);
        int z0 = max(cz - r, 0), z1 = min(cz + r, GR - 1);
        for (int z = z0; z <= z1; ++z) {
            for (int y = y0; y <= y1; ++y) {
                int rowbase = (z * GR + y) * GR;
                unsigned s0 = cstart[rowbase + x0];
                unsigned s1 = cstart[rowbase + x1 + 1];
                for (unsigned u = s0; u < s1; ++u)
                    best = u64min(best, pack_key(px, py, pz, S[u]));
            }
        }
        bool covered = (x0 == 0) & (x1 == GR-1) & (y0 == 0) &
                       (y1 == GR-1) & (z0 == 0) & (z1 == GR-1);
        if (covered) break;
        float blo = 1.0e30f;
        if (cx - r > 0)      blo = fminf(blo, px - (float)(cx - r) * HCELL);
        if (cx + r < GR - 1) blo = fminf(blo, (float)(cx + r + 1) * HCELL - px);
        if (cy - r > 0)      blo = fminf(blo, py - (float)(cy - r) * HCELL);
        if (cy + r < GR - 1) blo = fminf(blo, (float)(cy + r + 1) * HCELL - py);
        if (cz - r > 0)      blo = fminf(blo, pz - (float)(cz - r) * HCELL);
        if (cz + r < GR - 1) blo = fminf(blo, (float)(cz + r + 1) * HCELL - pz);
        float bd2 = __uint_as_float((unsigned)(best >> 32));
        if (bd2 <= blo * blo) break;   // NaN (empty box) -> false -> expand
    }
    return best;
}

// Dispatch 2: queries + inlined per-vertex epilogue. Pred lane knows its own
// nearest -> normal/laplacian/spatial terms computed right here (no finish
// dispatch, no nearestIdx buffer). Last block (done-counter) combines.
__global__ __launch_bounds__(256) void query_kernel(const float* __restrict__ relpos,
                                                    const int* __restrict__ label,
                                                    const float4* __restrict__ sortP,
                                                    const float4* __restrict__ sortG,
                                                    const unsigned* __restrict__ startP,
                                                    const unsigned* __restrict__ startG,
                                                    const float* __restrict__ pnnA,
                                                    const float* __restrict__ pnnB,
                                                    const float* __restrict__ nsumA,
                                                    const float* __restrict__ nsumB,
                                                    const float* __restrict__ degA,
                                                    const float* __restrict__ degB,
                                                    const float* __restrict__ gtnA,
                                                    const float* __restrict__ gtnB,
                                                    float* __restrict__ accum,
                                                    unsigned* __restrict__ done,
                                                    float* __restrict__ out) {
    __shared__ float bsum[6];
    __shared__ bool isLast;
    int b = blockIdx.x, t = threadIdx.x;
    if (t < 6) bsum[t] = 0.0f;
    __syncthreads();
    float r0 = 0.f, r1 = 0.f, r2 = 0.f, r3 = 0.f, r4 = 0.f, r5 = 0.f;
    bool is_pred = (b < PQ_BLOCKS);
    if (is_pred) {
        int qid = b * 256 + t;               // < 8192 exact
        float4 P = sortP[qid];
        float px = P.x, py = P.y, pz = P.z;
        unsigned long long key = lane_nn(px, py, pz, sortG, startG);
        int v = __float_as_int(P.w);         // original pred index
        int nearest = (int)(unsigned)(key & 0xffffffffu);
        r0 = __uint_as_float((unsigned)(key >> 32));   // dmin

        // normal consistency (sum A+B halves, normalize on the fly)
        float ax = pnnA[3*v]   + pnnB[3*v];
        float ay = pnnA[3*v+1] + pnnB[3*v+1];
        float az = pnnA[3*v+2] + pnnB[3*v+2];
        float an = fmaxf(sqrtf(ax*ax + ay*ay + az*az), EPSF);
        float gx = gtnA[3*nearest]   + gtnB[3*nearest];
        float gy = gtnA[3*nearest+1] + gtnB[3*nearest+1];
        float gz = gtnA[3*nearest+2] + gtnB[3*nearest+2];
        float gn = fmaxf(sqrtf(gx*gx + gy*gy + gz*gz), EPSF);
        float nx = ax/an - gx/gn, ny = ay/an - gy/gn, nz = az/an - gz/gn;
        r1 = nx*nx + ny*ny + nz*nz;          // sse

        // laplacian
        float d = fmaxf(degA[v] + degB[v], 1.0f);
        float lx = (nsumA[3*v]   + nsumB[3*v])   / d - px;
        float ly = (nsumA[3*v+1] + nsumB[3*v+1]) / d - py;
        float lz = (nsumA[3*v+2] + nsumB[3*v+2]) / d - pz;
        r2 = sqrtf(lx*lx + ly*ly + lz*lz);   // lapn

        // grid-sample target (nearest, align_corners=True, zeros padding)
        int ix = (int)rintf(px * 95.0f), iy = (int)rintf(py * 95.0f), iz = (int)rintf(pz * 95.0f);
        bool inb = (ix >= 0) & (ix < 96) & (iy >= 0) & (iy < 96) & (iz >= 0) & (iz < 96);
        int ixc = min(max(ix, 0), 95), iyc = min(max(iy, 0), 95), izc = min(max(iz, 0), 95);
        bool pos = inb && (label[(izc*96 + iyc)*96 + ixc] == 1);

        float p = fminf(fmaxf(relpos[v], EPSF), 1.0f - EPSF);
        float om = 1.0f - p;
        if (pos) { r3 = 1.0f; r4 = om*om*logf(p); }
        else     { r5 = p*p*logf(om); }
    } else {
        int qid = (b - PQ_BLOCKS) * 256 + t;
        if (qid < NG) {                      // per-lane guard (last block partial)
            float4 Q = sortG[qid];
            unsigned long long key = lane_nn(Q.x, Q.y, Q.z, sortP, startP);
            r0 = __uint_as_float((unsigned)(key >> 32));
        }
    }
    r0 = wave_sum(r0);
    if (is_pred) {
        r1 = wave_sum(r1); r2 = wave_sum(r2); r3 = wave_sum(r3);
        r4 = wave_sum(r4); r5 = wave_sum(r5);
    }
    if ((t & 63) == 0) {
        atomicAdd(&bsum[0], r0);
        if (is_pred) {
            atomicAdd(&bsum[1], r1); atomicAdd(&bsum[2], r2);
            atomicAdd(&bsum[3], r3); atomicAdd(&bsum[4], r4);
            atomicAdd(&bsum[5], r5);
        }
    }
    __syncthreads();
    if (t == 0) {
        if (is_pred) {
            atomicAdd(&accum[0], bsum[0]); atomicAdd(&accum[1], bsum[1]);
            atomicAdd(&accum[2], bsum[2]); atomicAdd(&accum[3], bsum[3]);
            atomicAdd(&accum[4], bsum[4]); atomicAdd(&accum[5], bsum[5]);
        } else {
            atomicAdd(&accum[6], bsum[0]);
        }
        __threadfence();                     // publish before done-count
        unsigned prev = atomicAdd(done, 1u);
        isLast = (prev == D2_BLOCKS - 1);
    }
    __syncthreads();
    if (isLast && t == 0) {
        __threadfence();
        float sum_row = __hip_atomic_load(&accum[0], __ATOMIC_RELAXED, __HIP_MEMORY_SCOPE_AGENT);
        float sse_t   = __hip_atomic_load(&accum[1], __ATOMIC_RELAXED, __HIP_MEMORY_SCOPE_AGENT);
        float lap_t   = __hip_atomic_load(&accum[2], __ATOMIC_RELAXED, __HIP_MEMORY_SCOPE_AGENT);
        float pc      = __hip_atomic_load(&accum[3], __ATOMIC_RELAXED, __HIP_MEMORY_SCOPE_AGENT);
        float SX      = __hip_atomic_load(&accum[4], __ATOMIC_RELAXED, __HIP_MEMORY_SCOPE_AGENT);
        float SY      = __hip_atomic_load(&accum[5], __ATOMIC_RELAXED, __HIP_MEMORY_SCOPE_AGENT);
        float sum_col = __hip_atomic_load(&accum[6], __ATOMIC_RELAXED, __HIP_MEMORY_SCOPE_AGENT);
        float tot = (float)NP;
        float alpha = (tot - pc) / (tot + EPSF);
        float spatial = (-alpha * SX - (1.0f - alpha) * SY) / (tot + EPSF);
        float distance = sum_row / (float)NP + sum_col / (float)NG;
        float normal = sse_t / (float)(NP * 3);
        float lapm = lap_t / (float)NP;
        out[0] = spatial + 1.0f * distance + 0.01f * normal + 0.1f * lapm;
    }
}

extern "C" void kernel_launch(void* const* d_in, const int* in_sizes, int n_in,
                              void* d_out, int out_size, void* d_ws, size_t ws_size,
                              hipStream_t stream) {
    const float* pred   = (const float*)d_in[0];   // [8192,3]
    const float* relpos = (const float*)d_in[1];   // [8192]
    const float* gt     = (const float*)d_in[2];   // [12000,3]
    const int*   pfaces = (const int*)d_in[3];     // [16384,3]
    const int*   gfaces = (const int*)d_in[4];     // [24000,3]
    const int*   label  = (const int*)d_in[5];     // [1,1,96,96,96]
    float* out = (float*)d_out;

    char* ws = (char*)d_ws;
    unsigned* startP  = (unsigned*)(ws + OFF_STARTP);
    unsigned* startG  = (unsigned*)(ws + OFF_STARTG);
    float4*   sortP   = (float4*)(ws + OFF_SORTP);
    float4*   sortG   = (float4*)(ws + OFF_SORTG);
    float*    pnnA    = (float*)(ws + OFF_PNNA);
    float*    pnnB    = (float*)(ws + OFF_PNNB);
    float*    nsumA   = (float*)(ws + OFF_NSUMA);
    float*    nsumB   = (float*)(ws + OFF_NSUMB);
    float*    degA    = (float*)(ws + OFF_DEGA);
    float*    degB    = (float*)(ws + OFF_DEGB);
    float*    gtnA    = (float*)(ws + OFF_GTNA);
    float*    gtnB    = (float*)(ws + OFF_GTNB);
    float*    accum   = (float*)(ws + OFF_ACCUM);
    unsigned* done    = (unsigned*)(ws + OFF_DONE);

    // d1: grid build (b0,b1) || zero (b2) || face accumulation (b3..b8)
    hipLaunchKernelGGL(build_kernel, dim3(9), dim3(1024), D1_LDS_BYTES, stream,
                       pred, gt, pfaces, gfaces, startP, startG, sortP, sortG,
                       pnnA, pnnB, nsumA, nsumB, degA, degB, gtnA, gtnB,
                       accum, done);
    // d2: lane-per-query NN + inlined epilogue + last-block combine
    hipLaunchKernelGGL(query_kernel, dim3(D2_BLOCKS), dim3(256), 0, stream,
                       relpos, label, sortP, sortG, startP, startG,
                       pnnA, pnnB, nsumA, nsumB, degA, degB, gtnA, gtnB,
                       accum, done, out);
}

// Round 4
// 154.507 us; speedup vs baseline: 1.5914x; 1.5914x over previous
//
#include <hip/hip_runtime.h>
#include <math.h>

// Problem constants (fixed by setup_inputs)
#define NP 8192      // pred vertices
#define NG 12000     // gt vertices
#define NFP 16384    // pred faces
#define NFG 24000    // gt faces
#define EPSF 1e-6f

// uniform grid for NN: 16^3 cells over [0,1]^3, ~3 gt / ~2 pred per cell
#define GR 16
#define NC (GR*GR*GR)        // 4096
#define HCELL 0.0625f        // 1/16, exact power of two

// D1: 2 build blocks + zero blocks (1024 thr)
#define N_ZERO 93353                      // floats gtn..done contiguous
#define ZERO_BLOCKS ((N_ZERO + 1023) / 1024)      // 92
#define D1_BLOCKS (2 + ZERO_BLOCKS)               // 94
// D2: gt->pred queries (one lane per query) || face scatter (global atomics)
#define GQ_BLOCKS ((NG + 255) / 256)              // 47 (last block 224 active)
#define FACE_BLOCKS ((NFG + NFP + 255) / 256)     // 158
#define MID_BLOCKS (GQ_BLOCKS + FACE_BLOCKS)      // 205
// D3: pred->gt queries + inlined epilogue + combine
#define PQ_BLOCKS (NP / 256)                      // 32

// ---- workspace layout (bytes) ----
static constexpr size_t OFF_STARTP = 0;        // (NC+1) u32, [NC]=NP
static constexpr size_t OFF_STARTG = 16640;    // (NC+1) u32, [NC]=NG
static constexpr size_t OFF_SORTP  = 33280;    // 8192  float4 (x,y,z,idx-bits)
static constexpr size_t OFF_SORTG  = 164352;   // 12000 float4
static constexpr size_t OFF_GTN    = 356352;   // NG*3 f32 gt normal accum   <- zero region start
static constexpr size_t OFF_PNN    = 500352;   // NP*3 f32 pred normal accum
static constexpr size_t OFF_NSUM   = 598656;   // NP*3 f32 laplacian neighbor sum
static constexpr size_t OFF_DEG    = 696960;   // NP   f32 laplacian degree
static constexpr size_t OFF_ACCUM  = 729728;   // 8 f32 global accumulators
static constexpr size_t OFF_DONE   = 729760;   // 1 u32 done-counter         <- zero region end

__device__ __forceinline__ int cell_of(float x) {
    int c = (int)(x * (float)GR);
    return min(max(c, 0), GR - 1);
}

// One block builds one point set: histogram -> shuffle scan -> start[] ->
// scatter into cell-sorted order via LDS cursor table. (Proven: never in
// top-5 across rounds 0-2.)
__device__ __forceinline__ void build_cells(const float* __restrict__ pts, int n,
                                            unsigned* __restrict__ start,
                                            float4* __restrict__ sorted,
                                            unsigned* h, unsigned* wsum) {
    int t = threadIdx.x;                 // 0..1023
    int lane = t & 63, wid = t >> 6;     // 16 waves
    for (int i = t; i < NC; i += 1024) h[i] = 0u;
    __syncthreads();
    for (int i = t; i < n; i += 1024) {
        int c = (cell_of(pts[3*i+2]) * GR + cell_of(pts[3*i+1])) * GR + cell_of(pts[3*i]);
        atomicAdd(&h[c], 1u);
    }
    __syncthreads();
    unsigned a0 = h[4*t], a1 = h[4*t+1], a2 = h[4*t+2], a3 = h[4*t+3];
    unsigned tsum = a0 + a1 + a2 + a3;
    unsigned x = tsum;
    #pragma unroll
    for (int off = 1; off < 64; off <<= 1) {
        unsigned y = __shfl_up(x, off, 64);
        if (lane >= off) x += y;
    }
    if (lane == 63) wsum[wid] = x;       // wave totals
    __syncthreads();
    if (t < 16) {                        // scan 16 wave totals inside wave 0
        unsigned w = wsum[t];
        #pragma unroll
        for (int off = 1; off < 16; off <<= 1) {
            unsigned y = __shfl_up(w, off, 64);
            if (t >= off) w += y;
        }
        wsum[t] = w;                     // inclusive
    }
    __syncthreads();
    unsigned base = (wid ? wsum[wid-1] : 0u) + (x - tsum);  // exclusive prefix
    unsigned e0 = base, e1 = base + a0, e2 = base + a0 + a1, e3 = base + a0 + a1 + a2;
    start[4*t] = e0; start[4*t+1] = e1; start[4*t+2] = e2; start[4*t+3] = e3;
    h[4*t] = e0; h[4*t+1] = e1; h[4*t+2] = e2; h[4*t+3] = e3;  // reuse as cursor
    __syncthreads();
    for (int i = t; i < n; i += 1024) {
        float px = pts[3*i], py = pts[3*i+1], pz = pts[3*i+2];
        int c = (cell_of(pz) * GR + cell_of(py)) * GR + cell_of(px);
        unsigned pos = atomicAdd(&h[c], 1u);
        sorted[pos] = make_float4(px, py, pz, __int_as_float(i));
    }
    if (t == 0) start[NC] = (unsigned)n;   // end sentinel
}

// Dispatch 1: b0 = pred build, b1 = gt build, b>=2 zero the atomic
// accumulation region (gtn..done, contiguous).
__global__ __launch_bounds__(1024) void build_kernel(const float* __restrict__ pred,
                                                     const float* __restrict__ gt,
                                                     unsigned* __restrict__ startP,
                                                     unsigned* __restrict__ startG,
                                                     float4* __restrict__ sortP,
                                                     float4* __restrict__ sortG,
                                                     float* __restrict__ zero) {
    __shared__ unsigned h[NC];
    __shared__ unsigned wsum[16];
    if (blockIdx.x == 0) {
        build_cells(pred, NP, startP, sortP, h, wsum);
    } else if (blockIdx.x == 1) {
        build_cells(gt, NG, startG, sortG, h, wsum);
    } else {
        int i = (blockIdx.x - 2) * 1024 + threadIdx.x;
        if (i < N_ZERO) zero[i] = 0.0f;
    }
}

__device__ __forceinline__ float wave_sum(float x) {
    #pragma unroll
    for (int o = 32; o > 0; o >>= 1) x += __shfl_down(x, o, 64);
    return x;
}

__device__ __forceinline__ unsigned long long u64min(unsigned long long a,
                                                     unsigned long long b) {
    return a < b ? a : b;
}

__device__ __forceinline__ unsigned long long pack_key(float px, float py, float pz,
                                                       float4 q) {
    float ddx = px - q.x, ddy = py - q.y, ddz = pz - q.z;
    float d2 = fmaf(ddx, ddx, fmaf(ddy, ddy, ddz*ddz));
    return ((unsigned long long)__float_as_uint(d2) << 32) |
           (unsigned)__float_as_int(q.w);
}

// One LANE per query: no cross-lane reduce, all point loads independent.
// Adjacent lanes hold cell-sorted neighboring queries -> convergent loop
// bounds, L1-hot spans. Expanding box with exact termination bound.
__device__ __forceinline__ unsigned long long lane_nn(float px, float py, float pz,
                                                      const float4* __restrict__ S,
                                                      const unsigned* __restrict__ cstart) {
    int cx = cell_of(px), cy = cell_of(py), cz = cell_of(pz);
    unsigned long long best = 0xFFFFFFFFFFFFFFFFULL;
    for (int r = 1; ; ++r) {
        int x0 = max(cx - r, 0), x1 = min(cx + r, GR - 1);
        int y0 = max(cy - r, 0), y1 = min(cy + r, GR - 1);
        int z0 = max(cz - r, 0), z1 = min(cz + r, GR - 1);
        for (int z = z0; z <= z1; ++z) {
            for (int y = y0; y <= y1; ++y) {
                int rowbase = (z * GR + y) * GR;
                unsigned s0 = cstart[rowbase + x0];
                unsigned s1 = cstart[rowbase + x1 + 1];
                for (unsigned u = s0; u < s1; ++u)
                    best = u64min(best, pack_key(px, py, pz, S[u]));
            }
        }
        bool covered = (x0 == 0) & (x1 == GR-1) & (y0 == 0) &
                       (y1 == GR-1) & (z0 == 0) & (z1 == GR-1);
        if (covered) break;
        float blo = 1.0e30f;
        if (cx - r > 0)      blo = fminf(blo, px - (float)(cx - r) * HCELL);
        if (cx + r < GR - 1) blo = fminf(blo, (float)(cx + r + 1) * HCELL - px);
        if (cy - r > 0)      blo = fminf(blo, py - (float)(cy - r) * HCELL);
        if (cy + r < GR - 1) blo = fminf(blo, (float)(cy + r + 1) * HCELL - py);
        if (cz - r > 0)      blo = fminf(blo, pz - (float)(cz - r) * HCELL);
        if (cz + r < GR - 1) blo = fminf(blo, (float)(cz + r + 1) * HCELL - pz);
        float bd2 = __uint_as_float((unsigned)(best >> 32));
        if (bd2 <= blo * blo) break;   // NaN (empty box) -> false -> expand
    }
    return best;
}

// Dispatch 2: gt->pred queries (read sortP/startP only) CONCURRENT with the
// face-normal/laplacian scatter (global atomics -- proven cheap in round 0;
// the LDS-resident variant was the 100+ us disaster of rounds 2-3).
__global__ __launch_bounds__(256) void mid_kernel(const float* __restrict__ pred,
                                                  const int* __restrict__ pf,
                                                  const float* __restrict__ gt,
                                                  const int* __restrict__ gf,
                                                  const float4* __restrict__ sortP,
                                                  const unsigned* __restrict__ startP,
                                                  float* __restrict__ gtn,
                                                  float* __restrict__ pnn,
                                                  float* __restrict__ nsum,
                                                  float* __restrict__ deg,
                                                  float* __restrict__ accum) {
    int b = blockIdx.x;
    if (b < GQ_BLOCKS) {
        __shared__ float bs;
        if (threadIdx.x == 0) bs = 0.0f;
        __syncthreads();
        int qid = b * 256 + threadIdx.x;
        float r0 = 0.0f;
        if (qid < NG) {
            const float4* SG = (const float4*)nullptr;  // (unused placeholder)
            (void)SG;
            float gx = gt[0]; (void)gx;  // no-op: keep signature simple
        }
        if (qid < NG) {
            // query point = gt vertex (original order is fine for a pure min-sum)
            float px = gt[3*qid], py = gt[3*qid+1], pz = gt[3*qid+2];
            unsigned long long key = lane_nn(px, py, pz, sortP, startP);
            r0 = __uint_as_float((unsigned)(key >> 32));
        }
        r0 = wave_sum(r0);
        if ((threadIdx.x & 63) == 0) atomicAdd(&bs, r0);
        __syncthreads();
        if (threadIdx.x == 0) atomicAdd(&accum[6], bs);
    } else {
        int t = (b - GQ_BLOCKS) * 256 + threadIdx.x;
        if (t < NFG) {
            int i0 = gf[3*t], i1 = gf[3*t+1], i2 = gf[3*t+2];
            float ax = gt[3*i0], ay = gt[3*i0+1], az = gt[3*i0+2];
            float bx = gt[3*i1], by = gt[3*i1+1], bz = gt[3*i1+2];
            float cx = gt[3*i2], cy = gt[3*i2+1], cz = gt[3*i2+2];
            float ux = bx-ax, uy = by-ay, uz = bz-az;
            float wx = cx-ax, wy = cy-ay, wz = cz-az;
            float nx = uy*wz - uz*wy, ny = uz*wx - ux*wz, nz = ux*wy - uy*wx;
            atomicAdd(&gtn[3*i0+0], nx); atomicAdd(&gtn[3*i0+1], ny); atomicAdd(&gtn[3*i0+2], nz);
            atomicAdd(&gtn[3*i1+0], nx); atomicAdd(&gtn[3*i1+1], ny); atomicAdd(&gtn[3*i1+2], nz);
            atomicAdd(&gtn[3*i2+0], nx); atomicAdd(&gtn[3*i2+1], ny); atomicAdd(&gtn[3*i2+2], nz);
        } else if (t < NFG + NFP) {
            int u = t - NFG;
            int i0 = pf[3*u], i1 = pf[3*u+1], i2 = pf[3*u+2];
            float ax = pred[3*i0], ay = pred[3*i0+1], az = pred[3*i0+2];
            float bx = pred[3*i1], by = pred[3*i1+1], bz = pred[3*i1+2];
            float cx = pred[3*i2], cy = pred[3*i2+1], cz = pred[3*i2+2];
            float ux = bx-ax, uy = by-ay, uz = bz-az;
            float wx = cx-ax, wy = cy-ay, wz = cz-az;
            float nx = uy*wz - uz*wy, ny = uz*wx - ux*wz, nz = ux*wy - uy*wx;
            atomicAdd(&pnn[3*i0+0], nx); atomicAdd(&pnn[3*i0+1], ny); atomicAdd(&pnn[3*i0+2], nz);
            atomicAdd(&pnn[3*i1+0], nx); atomicAdd(&pnn[3*i1+1], ny); atomicAdd(&pnn[3*i1+2], nz);
            atomicAdd(&pnn[3*i2+0], nx); atomicAdd(&pnn[3*i2+1], ny); atomicAdd(&pnn[3*i2+2], nz);
            atomicAdd(&nsum[3*i0+0], bx+cx); atomicAdd(&nsum[3*i0+1], by+cy); atomicAdd(&nsum[3*i0+2], bz+cz);
            atomicAdd(&nsum[3*i1+0], cx+ax); atomicAdd(&nsum[3*i1+1], cy+ay); atomicAdd(&nsum[3*i1+2], cz+az);
            atomicAdd(&nsum[3*i2+0], ax+bx); atomicAdd(&nsum[3*i2+1], ay+by); atomicAdd(&nsum[3*i2+2], az+bz);
            atomicAdd(&deg[i0], 2.0f); atomicAdd(&deg[i1], 2.0f); atomicAdd(&deg[i2], 2.0f);
        }
    }
}

// Dispatch 3: pred->gt queries + inlined per-vertex epilogue + last-block
// combine (face data complete after D2; accum[6] complete after D2).
__global__ __launch_bounds__(256) void pred_kernel(const float* __restrict__ relpos,
                                                   const int* __restrict__ label,
                                                   const float4* __restrict__ sortP,
                                                   const float4* __restrict__ sortG,
                                                   const unsigned* __restrict__ startG,
                                                   const float* __restrict__ pnn,
                                                   const float* __restrict__ gtn,
                                                   const float* __restrict__ nsum,
                                                   const float* __restrict__ deg,
                                                   float* __restrict__ accum,
                                                   unsigned* __restrict__ done,
                                                   float* __restrict__ out) {
    __shared__ float bsum[6];
    __shared__ bool isLast;
    int b = blockIdx.x, t = threadIdx.x;
    if (t < 6) bsum[t] = 0.0f;
    __syncthreads();

    int qid = b * 256 + t;                   // < 8192 exact
    float4 P = sortP[qid];
    float px = P.x, py = P.y, pz = P.z;
    unsigned long long key = lane_nn(px, py, pz, sortG, startG);
    int v = __float_as_int(P.w);             // original pred index
    int nearest = (int)(unsigned)(key & 0xffffffffu);
    float r0 = __uint_as_float((unsigned)(key >> 32));   // dmin

    // normal consistency (normalize both accumulators on the fly)
    float ax = pnn[3*v], ay = pnn[3*v+1], az = pnn[3*v+2];
    float an = fmaxf(sqrtf(ax*ax + ay*ay + az*az), EPSF);
    float gx = gtn[3*nearest], gy = gtn[3*nearest+1], gz = gtn[3*nearest+2];
    float gn = fmaxf(sqrtf(gx*gx + gy*gy + gz*gz), EPSF);
    float nx = ax/an - gx/gn, ny = ay/an - gy/gn, nz = az/an - gz/gn;
    float r1 = nx*nx + ny*ny + nz*nz;        // sse

    // laplacian
    float d = fmaxf(deg[v], 1.0f);
    float lx = nsum[3*v]/d - px, ly = nsum[3*v+1]/d - py, lz = nsum[3*v+2]/d - pz;
    float r2 = sqrtf(lx*lx + ly*ly + lz*lz); // lapn

    // grid-sample target (nearest, align_corners=True, zeros padding)
    int ix = (int)rintf(px * 95.0f), iy = (int)rintf(py * 95.0f), iz = (int)rintf(pz * 95.0f);
    bool inb = (ix >= 0) & (ix < 96) & (iy >= 0) & (iy < 96) & (iz >= 0) & (iz < 96);
    int ixc = min(max(ix, 0), 95), iyc = min(max(iy, 0), 95), izc = min(max(iz, 0), 95);
    bool pos = inb && (label[(izc*96 + iyc)*96 + ixc] == 1);

    float p = fminf(fmaxf(relpos[v], EPSF), 1.0f - EPSF);
    float om = 1.0f - p;
    float r3 = 0.f, r4 = 0.f, r5 = 0.f;
    if (pos) { r3 = 1.0f; r4 = om*om*logf(p); }
    else     { r5 = p*p*logf(om); }

    r0 = wave_sum(r0); r1 = wave_sum(r1); r2 = wave_sum(r2);
    r3 = wave_sum(r3); r4 = wave_sum(r4); r5 = wave_sum(r5);
    if ((t & 63) == 0) {
        atomicAdd(&bsum[0], r0); atomicAdd(&bsum[1], r1); atomicAdd(&bsum[2], r2);
        atomicAdd(&bsum[3], r3); atomicAdd(&bsum[4], r4); atomicAdd(&bsum[5], r5);
    }
    __syncthreads();
    if (t == 0) {
        atomicAdd(&accum[0], bsum[0]); atomicAdd(&accum[1], bsum[1]);
        atomicAdd(&accum[2], bsum[2]); atomicAdd(&accum[3], bsum[3]);
        atomicAdd(&accum[4], bsum[4]); atomicAdd(&accum[5], bsum[5]);
        __threadfence();                     // publish before done-count
        unsigned prev = atomicAdd(done, 1u);
        isLast = (prev == PQ_BLOCKS - 1);
    }
    __syncthreads();
    if (isLast && t == 0) {
        __threadfence();
        float sum_row = __hip_atomic_load(&accum[0], __ATOMIC_RELAXED, __HIP_MEMORY_SCOPE_AGENT);
        float sse_t   = __hip_atomic_load(&accum[1], __ATOMIC_RELAXED, __HIP_MEMORY_SCOPE_AGENT);
        float lap_t   = __hip_atomic_load(&accum[2], __ATOMIC_RELAXED, __HIP_MEMORY_SCOPE_AGENT);
        float pc      = __hip_atomic_load(&accum[3], __ATOMIC_RELAXED, __HIP_MEMORY_SCOPE_AGENT);
        float SX      = __hip_atomic_load(&accum[4], __ATOMIC_RELAXED, __HIP_MEMORY_SCOPE_AGENT);
        float SY      = __hip_atomic_load(&accum[5], __ATOMIC_RELAXED, __HIP_MEMORY_SCOPE_AGENT);
        float sum_col = __hip_atomic_load(&accum[6], __ATOMIC_RELAXED, __HIP_MEMORY_SCOPE_AGENT);
        float tot = (float)NP;
        float alpha = (tot - pc) / (tot + EPSF);
        float spatial = (-alpha * SX - (1.0f - alpha) * SY) / (tot + EPSF);
        float distance = sum_row / (float)NP + sum_col / (float)NG;
        float normal = sse_t / (float)(NP * 3);
        float lapm = lap_t / (float)NP;
        out[0] = spatial + 1.0f * distance + 0.01f * normal + 0.1f * lapm;
    }
}

extern "C" void kernel_launch(void* const* d_in, const int* in_sizes, int n_in,
                              void* d_out, int out_size, void* d_ws, size_t ws_size,
                              hipStream_t stream) {
    const float* pred   = (const float*)d_in[0];   // [8192,3]
    const float* relpos = (const float*)d_in[1];   // [8192]
    const float* gt     = (const float*)d_in[2];   // [12000,3]
    const int*   pfaces = (const int*)d_in[3];     // [16384,3]
    const int*   gfaces = (const int*)d_in[4];     // [24000,3]
    const int*   label  = (const int*)d_in[5];     // [1,1,96,96,96]
    float* out = (float*)d_out;

    char* ws = (char*)d_ws;
    unsigned* startP  = (unsigned*)(ws + OFF_STARTP);
    unsigned* startG  = (unsigned*)(ws + OFF_STARTG);
    float4*   sortP   = (float4*)(ws + OFF_SORTP);
    float4*   sortG   = (float4*)(ws + OFF_SORTG);
    float*    gtn     = (float*)(ws + OFF_GTN);
    float*    pnn     = (float*)(ws + OFF_PNN);
    float*    nsum    = (float*)(ws + OFF_NSUM);
    float*    deg     = (float*)(ws + OFF_DEG);
    float*    accum   = (float*)(ws + OFF_ACCUM);
    unsigned* done    = (unsigned*)(ws + OFF_DONE);

    // d1: grid build (b0,b1) || zero atomic-accum region (b2..)
    hipLaunchKernelGGL(build_kernel, dim3(D1_BLOCKS), dim3(1024), 0, stream,
                       pred, gt, startP, startG, sortP, sortG,
                       (float*)(ws + OFF_GTN));
    // d2: gt->pred lane-per-query NN || face scatter (global atomics)
    hipLaunchKernelGGL(mid_kernel, dim3(MID_BLOCKS), dim3(256), 0, stream,
                       pred, pfaces, gt, gfaces, sortP, startP,
                       gtn, pnn, nsum, deg, accum);
    // d3: pred->gt lane-per-query NN + inlined epilogue + combine
    hipLaunchKernelGGL(pred_kernel, dim3(PQ_BLOCKS), dim3(256), 0, stream,
                       relpos, label, sortP, sortG, startG,
                       pnn, gtn, nsum, deg, accum, done, out);
}

// Round 5
// 144.019 us; speedup vs baseline: 1.7073x; 1.0728x over previous
//
#include <hip/hip_runtime.h>
#include <math.h>

// Problem constants (fixed by setup_inputs)
#define NP 8192      // pred vertices
#define NG 12000     // gt vertices
#define NFP 16384    // pred faces
#define NFG 24000    // gt faces
#define EPSF 1e-6f

// uniform grid for NN: 16^3 cells over [0,1]^3, ~3 gt / ~2 pred per cell
#define GR 16
#define NC (GR*GR*GR)        // 4096
#define HCELL 0.0625f        // 1/16, exact power of two

// D1: 2 build blocks + zero blocks (1024 thr)
#define N_ZERO 101545                             // floats gtn..done contiguous
#define ZERO_BLOCKS ((N_ZERO + 1023) / 1024)      // 100
#define D1_BLOCKS (2 + ZERO_BLOCKS)               // 102

// D2 (64-thr blocks): pred queries | gt queries | face scatter, all concurrent.
// Queries read only sorted arrays + cstart; faces write gtn/pnn/nsum/deg via
// global atomics (proven <=8us in round 0). No read/write overlap -> race-free.
#define PQB64 (NP / 64)                           // 128
#define GQB64 ((NG + 63) / 64)                    // 188 (last block 32 active)
#define FQB64 ((NFG + NFP + 63) / 64)             // 631
#define D2_BLOCKS (PQB64 + GQB64 + FQB64)         // 947

// D3: per-vertex epilogue + combine
#define FIN_BLOCKS (NP / 256)                     // 32

// ---- workspace layout (bytes) ----
static constexpr size_t OFF_STARTP = 0;        // (NC+1) u32, [NC]=NP
static constexpr size_t OFF_STARTG = 16640;    // (NC+1) u32, [NC]=NG
static constexpr size_t OFF_SORTP  = 33280;    // 8192  float4 (x,y,z,idx-bits)
static constexpr size_t OFF_SORTG  = 164352;   // 12000 float4
static constexpr size_t OFF_GTN    = 356352;   // NG*3 f32 gt normal accum   <- zero region start
static constexpr size_t OFF_PNN    = 500352;   // NP*3 f32 pred normal accum
static constexpr size_t OFF_NSUM   = 598656;   // NP*3 f32 laplacian neighbor sum
static constexpr size_t OFF_DEG    = 696960;   // NP   f32 laplacian degree
static constexpr size_t OFF_NEAR   = 729728;   // NP   i32 nearest gt (original idx)
static constexpr size_t OFF_ACCUM  = 762496;   // 8 f32 global accumulators
static constexpr size_t OFF_DONE   = 762528;   // 1 u32 done-counter          <- zero region end

__device__ __forceinline__ int cell_of(float x) {
    int c = (int)(x * (float)GR);
    return min(max(c, 0), GR - 1);
}

// One block builds one point set: histogram -> shuffle scan -> start[] ->
// scatter into cell-sorted order via LDS cursor table. (Proven cheap.)
__device__ __forceinline__ void build_cells(const float* __restrict__ pts, int n,
                                            unsigned* __restrict__ start,
                                            float4* __restrict__ sorted,
                                            unsigned* h, unsigned* wsum) {
    int t = threadIdx.x;                 // 0..1023
    int lane = t & 63, wid = t >> 6;     // 16 waves
    for (int i = t; i < NC; i += 1024) h[i] = 0u;
    __syncthreads();
    for (int i = t; i < n; i += 1024) {
        int c = (cell_of(pts[3*i+2]) * GR + cell_of(pts[3*i+1])) * GR + cell_of(pts[3*i]);
        atomicAdd(&h[c], 1u);
    }
    __syncthreads();
    unsigned a0 = h[4*t], a1 = h[4*t+1], a2 = h[4*t+2], a3 = h[4*t+3];
    unsigned tsum = a0 + a1 + a2 + a3;
    unsigned x = tsum;
    #pragma unroll
    for (int off = 1; off < 64; off <<= 1) {
        unsigned y = __shfl_up(x, off, 64);
        if (lane >= off) x += y;
    }
    if (lane == 63) wsum[wid] = x;       // wave totals
    __syncthreads();
    if (t < 16) {                        // scan 16 wave totals inside wave 0
        unsigned w = wsum[t];
        #pragma unroll
        for (int off = 1; off < 16; off <<= 1) {
            unsigned y = __shfl_up(w, off, 64);
            if (t >= off) w += y;
        }
        wsum[t] = w;                     // inclusive
    }
    __syncthreads();
    unsigned base = (wid ? wsum[wid-1] : 0u) + (x - tsum);  // exclusive prefix
    unsigned e0 = base, e1 = base + a0, e2 = base + a0 + a1, e3 = base + a0 + a1 + a2;
    start[4*t] = e0; start[4*t+1] = e1; start[4*t+2] = e2; start[4*t+3] = e3;
    h[4*t] = e0; h[4*t+1] = e1; h[4*t+2] = e2; h[4*t+3] = e3;  // reuse as cursor
    __syncthreads();
    for (int i = t; i < n; i += 1024) {
        float px = pts[3*i], py = pts[3*i+1], pz = pts[3*i+2];
        int c = (cell_of(pz) * GR + cell_of(py)) * GR + cell_of(px);
        unsigned pos = atomicAdd(&h[c], 1u);
        sorted[pos] = make_float4(px, py, pz, __int_as_float(i));
    }
    if (t == 0) start[NC] = (unsigned)n;   // end sentinel
}

// Dispatch 1: b0 = pred build, b1 = gt build, b>=2 zero the accumulation
// region (gtn..done, contiguous).
__global__ __launch_bounds__(1024) void build_kernel(const float* __restrict__ pred,
                                                     const float* __restrict__ gt,
                                                     unsigned* __restrict__ startP,
                                                     unsigned* __restrict__ startG,
                                                     float4* __restrict__ sortP,
                                                     float4* __restrict__ sortG,
                                                     float* __restrict__ zero) {
    __shared__ unsigned h[NC];
    __shared__ unsigned wsum[16];
    if (blockIdx.x == 0) {
        build_cells(pred, NP, startP, sortP, h, wsum);
    } else if (blockIdx.x == 1) {
        build_cells(gt, NG, startG, sortG, h, wsum);
    } else {
        int i = (blockIdx.x - 2) * 1024 + threadIdx.x;
        if (i < N_ZERO) zero[i] = 0.0f;
    }
}

__device__ __forceinline__ float wave_sum(float x) {
    #pragma unroll
    for (int o = 32; o > 0; o >>= 1) x += __shfl_down(x, o, 64);
    return x;
}

__device__ __forceinline__ unsigned long long u64min(unsigned long long a,
                                                     unsigned long long b) {
    return a < b ? a : b;
}

__device__ __forceinline__ unsigned long long pack_key(float px, float py, float pz,
                                                       float4 q) {
    float ddx = px - q.x, ddy = py - q.y, ddz = pz - q.z;
    float d2 = fmaf(ddx, ddx, fmaf(ddy, ddy, ddz*ddz));
    return ((unsigned long long)__float_as_uint(d2) << 32) |
           (unsigned)__float_as_int(q.w);
}

// One LANE per query, query points taken from the CELL-SORTED array so
// adjacent lanes process neighboring cells (convergent span bounds, L1-hot
// points -- round 4 queried in random order and paid ~2x for it).
// r=1 is fully unrolled (compile-time 9 rows): all 18 independent cstart
// loads issue up front instead of one dependent pair per row iteration.
// General expanding loop only for the ~0.02% of queries that need r>=2.
__device__ unsigned long long lane_nn(float px, float py, float pz,
                                      const float4* __restrict__ S,
                                      const unsigned* __restrict__ cstart) {
    int cx = cell_of(px), cy = cell_of(py), cz = cell_of(pz);
    unsigned long long best = 0xFFFFFFFFFFFFFFFFULL;
    {   // ---- r = 1 fast path, fully unrolled ----
        int x0 = max(cx - 1, 0), x1 = min(cx + 1, GR - 1);
        #pragma unroll
        for (int dz = -1; dz <= 1; ++dz) {
            #pragma unroll
            for (int dy = -1; dy <= 1; ++dy) {
                int z = cz + dz, y = cy + dy;
                if (z >= 0 && z < GR && y >= 0 && y < GR) {
                    int rowbase = (z * GR + y) * GR;
                    unsigned s0 = cstart[rowbase + x0];
                    unsigned s1 = cstart[rowbase + x1 + 1];
                    for (unsigned u = s0; u < s1; ++u)
                        best = u64min(best, pack_key(px, py, pz, S[u]));
                }
            }
        }
        bool covered = (cx - 1 <= 0) & (cx + 1 >= GR - 1) &
                       (cy - 1 <= 0) & (cy + 1 >= GR - 1) &
                       (cz - 1 <= 0) & (cz + 1 >= GR - 1);
        float blo = 1.0e30f;
        if (cx - 1 > 0)      blo = fminf(blo, px - (float)(cx - 1) * HCELL);
        if (cx + 1 < GR - 1) blo = fminf(blo, (float)(cx + 2) * HCELL - px);
        if (cy - 1 > 0)      blo = fminf(blo, py - (float)(cy - 1) * HCELL);
        if (cy + 1 < GR - 1) blo = fminf(blo, (float)(cy + 2) * HCELL - py);
        if (cz - 1 > 0)      blo = fminf(blo, pz - (float)(cz - 1) * HCELL);
        if (cz + 1 < GR - 1) blo = fminf(blo, (float)(cz + 2) * HCELL - pz);
        float bd2 = __uint_as_float((unsigned)(best >> 32));
        if (covered || (bd2 <= blo * blo)) return best;   // NaN -> expand
    }
    for (int r = 2; ; ++r) {   // ---- cold general path ----
        int x0 = max(cx - r, 0), x1 = min(cx + r, GR - 1);
        int y0 = max(cy - r, 0), y1 = min(cy + r, GR - 1);
        int z0 = max(cz - r, 0), z1 = min(cz + r, GR - 1);
        for (int z = z0; z <= z1; ++z) {
            for (int y = y0; y <= y1; ++y) {
                int rowbase = (z * GR + y) * GR;
                unsigned s0 = cstart[rowbase + x0];
                unsigned s1 = cstart[rowbase + x1 + 1];
                for (unsigned u = s0; u < s1; ++u)
                    best = u64min(best, pack_key(px, py, pz, S[u]));
            }
        }
        bool covered = (x0 == 0) & (x1 == GR-1) & (y0 == 0) &
                       (y1 == GR-1) & (z0 == 0) & (z1 == GR-1);
        if (covered) break;
        float blo = 1.0e30f;
        if (cx - r > 0)      blo = fminf(blo, px - (float)(cx - r) * HCELL);
        if (cx + r < GR - 1) blo = fminf(blo, (float)(cx + r + 1) * HCELL - px);
        if (cy - r > 0)      blo = fminf(blo, py - (float)(cy - r) * HCELL);
        if (cy + r < GR - 1) blo = fminf(blo, (float)(cy + r + 1) * HCELL - py);
        if (cz - r > 0)      blo = fminf(blo, pz - (float)(cz - r) * HCELL);
        if (cz + r < GR - 1) blo = fminf(blo, (float)(cz + r + 1) * HCELL - pz);
        float bd2 = __uint_as_float((unsigned)(best >> 32));
        if (bd2 <= blo * blo) break;
    }
    return best;
}

// Dispatch 2 (64-thr blocks = 1 wave each, 947 blocks):
//   [0,128)    pred->gt queries (sorted): nearestIdx + dmin sum
//   [128,316)  gt->pred queries (sorted): dmin sum
//   [316,947)  face scatter via global atomics (proven cheap in round 0)
__global__ __launch_bounds__(64) void work_kernel(const float* __restrict__ pred,
                                                  const int* __restrict__ pf,
                                                  const float* __restrict__ gt,
                                                  const int* __restrict__ gf,
                                                  const float4* __restrict__ sortP,
                                                  const float4* __restrict__ sortG,
                                                  const unsigned* __restrict__ startP,
                                                  const unsigned* __restrict__ startG,
                                                  float* __restrict__ gtn,
                                                  float* __restrict__ pnn,
                                                  float* __restrict__ nsum,
                                                  float* __restrict__ deg,
                                                  int* __restrict__ nearestIdx,
                                                  float* __restrict__ accum) {
    int b = blockIdx.x, t = threadIdx.x;
    if (b < PQB64) {
        int qid = b * 64 + t;                    // < 8192 exact
        float4 P = sortP[qid];
        unsigned long long key = lane_nn(P.x, P.y, P.z, sortG, startG);
        int v = __float_as_int(P.w);             // original pred index
        nearestIdx[v] = (int)(unsigned)(key & 0xffffffffu);
        float r0 = wave_sum(__uint_as_float((unsigned)(key >> 32)));
        if (t == 0) atomicAdd(&accum[0], r0);
    } else if (b < PQB64 + GQB64) {
        int qid = (b - PQB64) * 64 + t;
        float r0 = 0.0f;
        if (qid < NG) {
            float4 Q = sortG[qid];
            unsigned long long key = lane_nn(Q.x, Q.y, Q.z, sortP, startP);
            r0 = __uint_as_float((unsigned)(key >> 32));
        }
        r0 = wave_sum(r0);
        if (t == 0) atomicAdd(&accum[6], r0);
    } else {
        int f = (b - PQB64 - GQB64) * 64 + t;
        if (f < NFG) {
            int i0 = gf[3*f], i1 = gf[3*f+1], i2 = gf[3*f+2];
            float ax = gt[3*i0], ay = gt[3*i0+1], az = gt[3*i0+2];
            float bx = gt[3*i1], by = gt[3*i1+1], bz = gt[3*i1+2];
            float cx = gt[3*i2], cy = gt[3*i2+1], cz = gt[3*i2+2];
            float ux = bx-ax, uy = by-ay, uz = bz-az;
            float wx = cx-ax, wy = cy-ay, wz = cz-az;
            float nx = uy*wz - uz*wy, ny = uz*wx - ux*wz, nz = ux*wy - uy*wx;
            atomicAdd(&gtn[3*i0+0], nx); atomicAdd(&gtn[3*i0+1], ny); atomicAdd(&gtn[3*i0+2], nz);
            atomicAdd(&gtn[3*i1+0], nx); atomicAdd(&gtn[3*i1+1], ny); atomicAdd(&gtn[3*i1+2], nz);
            atomicAdd(&gtn[3*i2+0], nx); atomicAdd(&gtn[3*i2+1], ny); atomicAdd(&gtn[3*i2+2], nz);
        } else if (f < NFG + NFP) {
            int u = f - NFG;
            int i0 = pf[3*u], i1 = pf[3*u+1], i2 = pf[3*u+2];
            float ax = pred[3*i0], ay = pred[3*i0+1], az = pred[3*i0+2];
            float bx = pred[3*i1], by = pred[3*i1+1], bz = pred[3*i1+2];
            float cx = pred[3*i2], cy = pred[3*i2+1], cz = pred[3*i2+2];
            float ux = bx-ax, uy = by-ay, uz = bz-az;
            float wx = cx-ax, wy = cy-ay, wz = cz-az;
            float nx = uy*wz - uz*wy, ny = uz*wx - ux*wz, nz = ux*wy - uy*wx;
            atomicAdd(&pnn[3*i0+0], nx); atomicAdd(&pnn[3*i0+1], ny); atomicAdd(&pnn[3*i0+2], nz);
            atomicAdd(&pnn[3*i1+0], nx); atomicAdd(&pnn[3*i1+1], ny); atomicAdd(&pnn[3*i1+2], nz);
            atomicAdd(&pnn[3*i2+0], nx); atomicAdd(&pnn[3*i2+1], ny); atomicAdd(&pnn[3*i2+2], nz);
            atomicAdd(&nsum[3*i0+0], bx+cx); atomicAdd(&nsum[3*i0+1], by+cy); atomicAdd(&nsum[3*i0+2], bz+cz);
            atomicAdd(&nsum[3*i1+0], cx+ax); atomicAdd(&nsum[3*i1+1], cy+ay); atomicAdd(&nsum[3*i1+2], cz+az);
            atomicAdd(&nsum[3*i2+0], ax+bx); atomicAdd(&nsum[3*i2+1], ay+by); atomicAdd(&nsum[3*i2+2], az+bz);
            atomicAdd(&deg[i0], 2.0f); atomicAdd(&deg[i1], 2.0f); atomicAdd(&deg[i2], 2.0f);
        }
    }
}

// Dispatch 3: fully-parallel per-vertex epilogue; last block (done-counter)
// computes the final scalar. (Proven structure from round 1.)
__global__ __launch_bounds__(256) void finish_kernel(const float* __restrict__ pred,
                                                     const float* __restrict__ relpos,
                                                     const int* __restrict__ label,
                                                     const float* __restrict__ pnn,
                                                     const float* __restrict__ gtn,
                                                     const float* __restrict__ nsum,
                                                     const float* __restrict__ deg,
                                                     const int* __restrict__ nearestIdx,
                                                     float* __restrict__ accum,
                                                     unsigned* __restrict__ done,
                                                     float* __restrict__ out) {
    int v = blockIdx.x * 256 + threadIdx.x;     // < 8192 exact
    float px = pred[3*v], py = pred[3*v+1], pz = pred[3*v+2];
    int nearest = nearestIdx[v];

    // normal consistency (normalize both accumulators on the fly)
    float ax = pnn[3*v], ay = pnn[3*v+1], az = pnn[3*v+2];
    float an = fmaxf(sqrtf(ax*ax + ay*ay + az*az), EPSF);
    float gx = gtn[3*nearest], gy = gtn[3*nearest+1], gz = gtn[3*nearest+2];
    float gn = fmaxf(sqrtf(gx*gx + gy*gy + gz*gz), EPSF);
    float nx = ax/an - gx/gn, ny = ay/an - gy/gn, nz = az/an - gz/gn;
    float sse = nx*nx + ny*ny + nz*nz;

    // laplacian
    float d = fmaxf(deg[v], 1.0f);
    float lx = nsum[3*v]/d - px, ly = nsum[3*v+1]/d - py, lz = nsum[3*v+2]/d - pz;
    float lapn = sqrtf(lx*lx + ly*ly + lz*lz);

    // grid-sample target (nearest, align_corners=True, zeros padding)
    int ix = (int)rintf(px * 95.0f), iy = (int)rintf(py * 95.0f), iz = (int)rintf(pz * 95.0f);
    bool inb = (ix >= 0) & (ix < 96) & (iy >= 0) & (iy < 96) & (iz >= 0) & (iz < 96);
    int ixc = min(max(ix, 0), 95), iyc = min(max(iy, 0), 95), izc = min(max(iz, 0), 95);
    bool pos = inb && (label[(izc*96 + iyc)*96 + ixc] == 1);

    float p = fminf(fmaxf(relpos[v], EPSF), 1.0f - EPSF);
    float om = 1.0f - p;
    float pcnt = 0.0f, sx = 0.0f, sy = 0.0f;
    if (pos) { pcnt = 1.0f; sx = om*om*logf(p); }
    else     { sy = p*p*logf(om); }

    float r1 = wave_sum(sse), r2 = wave_sum(lapn), r3 = wave_sum(pcnt);
    float r4 = wave_sum(sx),  r5 = wave_sum(sy);
    __shared__ float bsum[5];
    __shared__ bool isLast;
    if (threadIdx.x < 5) bsum[threadIdx.x] = 0.0f;
    __syncthreads();
    if ((threadIdx.x & 63) == 0) {
        atomicAdd(&bsum[0], r1); atomicAdd(&bsum[1], r2); atomicAdd(&bsum[2], r3);
        atomicAdd(&bsum[3], r4); atomicAdd(&bsum[4], r5);
    }
    __syncthreads();
    if (threadIdx.x == 0) {
        atomicAdd(&accum[1], bsum[0]); atomicAdd(&accum[2], bsum[1]);
        atomicAdd(&accum[3], bsum[2]); atomicAdd(&accum[4], bsum[3]);
        atomicAdd(&accum[5], bsum[4]);
        __threadfence();                         // publish before done-count
        unsigned prev = atomicAdd(done, 1u);
        isLast = (prev == FIN_BLOCKS - 1);
    }
    __syncthreads();
    if (isLast && threadIdx.x == 0) {
        __threadfence();
        float sum_row = __hip_atomic_load(&accum[0], __ATOMIC_RELAXED, __HIP_MEMORY_SCOPE_AGENT);
        float sse_t   = __hip_atomic_load(&accum[1], __ATOMIC_RELAXED, __HIP_MEMORY_SCOPE_AGENT);
        float lap_t   = __hip_atomic_load(&accum[2], __ATOMIC_RELAXED, __HIP_MEMORY_SCOPE_AGENT);
        float pc      = __hip_atomic_load(&accum[3], __ATOMIC_RELAXED, __HIP_MEMORY_SCOPE_AGENT);
        float SX      = __hip_atomic_load(&accum[4], __ATOMIC_RELAXED, __HIP_MEMORY_SCOPE_AGENT);
        float SY      = __hip_atomic_load(&accum[5], __ATOMIC_RELAXED, __HIP_MEMORY_SCOPE_AGENT);
        float sum_col = __hip_atomic_load(&accum[6], __ATOMIC_RELAXED, __HIP_MEMORY_SCOPE_AGENT);
        float tot = (float)NP;
        float alpha = (tot - pc) / (tot + EPSF);
        float spatial = (-alpha * SX - (1.0f - alpha) * SY) / (tot + EPSF);
        float distance = sum_row / (float)NP + sum_col / (float)NG;
        float normal = sse_t / (float)(NP * 3);
        float lapm = lap_t / (float)NP;
        out[0] = spatial + 1.0f * distance + 0.01f * normal + 0.1f * lapm;
    }
}

extern "C" void kernel_launch(void* const* d_in, const int* in_sizes, int n_in,
                              void* d_out, int out_size, void* d_ws, size_t ws_size,
                              hipStream_t stream) {
    const float* pred   = (const float*)d_in[0];   // [8192,3]
    const float* relpos = (const float*)d_in[1];   // [8192]
    const float* gt     = (const float*)d_in[2];   // [12000,3]
    const int*   pfaces = (const int*)d_in[3];     // [16384,3]
    const int*   gfaces = (const int*)d_in[4];     // [24000,3]
    const int*   label  = (const int*)d_in[5];     // [1,1,96,96,96]
    float* out = (float*)d_out;

    char* ws = (char*)d_ws;
    unsigned* startP  = (unsigned*)(ws + OFF_STARTP);
    unsigned* startG  = (unsigned*)(ws + OFF_STARTG);
    float4*   sortP   = (float4*)(ws + OFF_SORTP);
    float4*   sortG   = (float4*)(ws + OFF_SORTG);
    float*    gtn     = (float*)(ws + OFF_GTN);
    float*    pnn     = (float*)(ws + OFF_PNN);
    float*    nsum    = (float*)(ws + OFF_NSUM);
    float*    deg     = (float*)(ws + OFF_DEG);
    int*      nearest = (int*)(ws + OFF_NEAR);
    float*    accum   = (float*)(ws + OFF_ACCUM);
    unsigned* done    = (unsigned*)(ws + OFF_DONE);

    // d1: grid build (b0,b1) || zero accumulation region (b2..)
    hipLaunchKernelGGL(build_kernel, dim3(D1_BLOCKS), dim3(1024), 0, stream,
                       pred, gt, startP, startG, sortP, sortG,
                       (float*)(ws + OFF_GTN));
    // d2: sorted lane-per-query NN (both directions) || face atomic scatter
    hipLaunchKernelGGL(work_kernel, dim3(D2_BLOCKS), dim3(64), 0, stream,
                       pred, pfaces, gt, gfaces, sortP, sortG, startP, startG,
                       gtn, pnn, nsum, deg, nearest, accum);
    // d3: per-vertex epilogue + last-block combine
    hipLaunchKernelGGL(finish_kernel, dim3(FIN_BLOCKS), dim3(256), 0, stream,
                       pred, relpos, label, pnn, gtn, nsum, deg, nearest,
                       accum, done, out);
}

// Round 6
// 132.179 us; speedup vs baseline: 1.8602x; 1.0896x over previous
//
#include <hip/hip_runtime.h>
#include <math.h>

// Problem constants (fixed by setup_inputs)
#define NP 8192      // pred vertices
#define NG 12000     // gt vertices
#define NFP 16384    // pred faces
#define NFG 24000    // gt faces
#define EPSF 1e-6f

// uniform grid for NN: 16^3 cells over [0,1]^3, ~3 gt / ~2 pred per cell
#define GR 16
#define NC (GR*GR*GR)        // 4096
#define HCELL 0.0625f        // 1/16, exact power of two
#define QL 16                // lanes cooperating per NN query (proven best)

// D1: 2 build blocks + zero blocks (1024 thr)
#define N_ZERO 101545                             // floats gtn..done contiguous
#define ZERO_BLOCKS ((N_ZERO + 1023) / 1024)      // 100
#define D1_BLOCKS (2 + ZERO_BLOCKS)               // 102

// D2 (1024-thr blocks): 64 queries/block (16 lanes each), LDS-staged search
// window; face blocks appended (global atomics, proven cheap round 0/1).
#define QPBLK 64
#define PQB (NP / QPBLK)                          // 128
#define GQB ((NG + QPBLK - 1) / QPBLK)            // 188 (last block 32 queries)
#define FB  ((NFG + NFP + 1023) / 1024)           // 40
#define D2_BLOCKS (PQB + GQB + FB)                // 356

// LDS staging capacities (overflow -> correct global fallback)
#define CAPP  4608           // points (float4) = 73728 B
#define CWCAP 1312           // cstart window entries (covers 5 z-slabs + 1)

// D3: per-vertex epilogue + combine
#define FIN_BLOCKS (NP / 256)                     // 32

// ---- workspace layout (bytes) ----
static constexpr size_t OFF_STARTP = 0;        // (NC+1) u32, [NC]=NP
static constexpr size_t OFF_STARTG = 16640;    // (NC+1) u32, [NC]=NG
static constexpr size_t OFF_SORTP  = 33280;    // 8192  float4 (x,y,z,idx-bits)
static constexpr size_t OFF_SORTG  = 164352;   // 12000 float4
static constexpr size_t OFF_GTN    = 356352;   // NG*3 f32 gt normal accum   <- zero region start
static constexpr size_t OFF_PNN    = 500352;   // NP*3 f32 pred normal accum
static constexpr size_t OFF_NSUM   = 598656;   // NP*3 f32 laplacian neighbor sum
static constexpr size_t OFF_DEG    = 696960;   // NP   f32 laplacian degree
static constexpr size_t OFF_NEAR   = 729728;   // NP   i32 nearest gt (original idx)
static constexpr size_t OFF_ACCUM  = 762496;   // 8 f32 global accumulators
static constexpr size_t OFF_DONE   = 762528;   // 1 u32 done-counter          <- zero region end

__device__ __forceinline__ int cell_of(float x) {
    int c = (int)(x * (float)GR);
    return min(max(c, 0), GR - 1);
}

// One block builds one point set: histogram -> shuffle scan -> start[] ->
// scatter into cell-sorted order via LDS cursor table. (Proven cheap.)
__device__ __forceinline__ void build_cells(const float* __restrict__ pts, int n,
                                            unsigned* __restrict__ start,
                                            float4* __restrict__ sorted,
                                            unsigned* h, unsigned* wsum) {
    int t = threadIdx.x;                 // 0..1023
    int lane = t & 63, wid = t >> 6;     // 16 waves
    for (int i = t; i < NC; i += 1024) h[i] = 0u;
    __syncthreads();
    for (int i = t; i < n; i += 1024) {
        int c = (cell_of(pts[3*i+2]) * GR + cell_of(pts[3*i+1])) * GR + cell_of(pts[3*i]);
        atomicAdd(&h[c], 1u);
    }
    __syncthreads();
    unsigned a0 = h[4*t], a1 = h[4*t+1], a2 = h[4*t+2], a3 = h[4*t+3];
    unsigned tsum = a0 + a1 + a2 + a3;
    unsigned x = tsum;
    #pragma unroll
    for (int off = 1; off < 64; off <<= 1) {
        unsigned y = __shfl_up(x, off, 64);
        if (lane >= off) x += y;
    }
    if (lane == 63) wsum[wid] = x;       // wave totals
    __syncthreads();
    if (t < 16) {                        // scan 16 wave totals inside wave 0
        unsigned w = wsum[t];
        #pragma unroll
        for (int off = 1; off < 16; off <<= 1) {
            unsigned y = __shfl_up(w, off, 64);
            if (t >= off) w += y;
        }
        wsum[t] = w;                     // inclusive
    }
    __syncthreads();
    unsigned base = (wid ? wsum[wid-1] : 0u) + (x - tsum);  // exclusive prefix
    unsigned e0 = base, e1 = base + a0, e2 = base + a0 + a1, e3 = base + a0 + a1 + a2;
    start[4*t] = e0; start[4*t+1] = e1; start[4*t+2] = e2; start[4*t+3] = e3;
    h[4*t] = e0; h[4*t+1] = e1; h[4*t+2] = e2; h[4*t+3] = e3;  // reuse as cursor
    __syncthreads();
    for (int i = t; i < n; i += 1024) {
        float px = pts[3*i], py = pts[3*i+1], pz = pts[3*i+2];
        int c = (cell_of(pz) * GR + cell_of(py)) * GR + cell_of(px);
        unsigned pos = atomicAdd(&h[c], 1u);
        sorted[pos] = make_float4(px, py, pz, __int_as_float(i));
    }
    if (t == 0) start[NC] = (unsigned)n;   // end sentinel
}

// Dispatch 1: b0 = pred build, b1 = gt build, b>=2 zero accumulation region.
__global__ __launch_bounds__(1024) void build_kernel(const float* __restrict__ pred,
                                                     const float* __restrict__ gt,
                                                     unsigned* __restrict__ startP,
                                                     unsigned* __restrict__ startG,
                                                     float4* __restrict__ sortP,
                                                     float4* __restrict__ sortG,
                                                     float* __restrict__ zero) {
    __shared__ unsigned h[NC];
    __shared__ unsigned wsum[16];
    if (blockIdx.x == 0) {
        build_cells(pred, NP, startP, sortP, h, wsum);
    } else if (blockIdx.x == 1) {
        build_cells(gt, NG, startG, sortG, h, wsum);
    } else {
        int i = (blockIdx.x - 2) * 1024 + threadIdx.x;
        if (i < N_ZERO) zero[i] = 0.0f;
    }
}

__device__ __forceinline__ float wave_sum(float x) {
    #pragma unroll
    for (int o = 32; o > 0; o >>= 1) x += __shfl_down(x, o, 64);
    return x;
}

__device__ __forceinline__ unsigned long long u64min(unsigned long long a,
                                                     unsigned long long b) {
    return a < b ? a : b;
}

__device__ __forceinline__ unsigned long long pack_key(float px, float py, float pz,
                                                       float4 q) {
    float ddx = px - q.x, ddy = py - q.y, ddz = pz - q.z;
    float d2 = fmaf(ddx, ddx, fmaf(ddy, ddy, ddz*ddz));
    return ((unsigned long long)__float_as_uint(d2) << 32) |
           (unsigned)__float_as_int(q.w);
}

// 16-lane group NN. r=1 reads from the block's LDS-staged window (points +
// cstart) when staged; identical arithmetic/order to global, so results are
// bit-identical. r>=2 expansion (~1e-4 of queries) and unstaged blocks use
// the global path.
__device__ unsigned long long group_nn(int lane, float px, float py, float pz,
                                       const float4* __restrict__ Sg,
                                       const unsigned* __restrict__ CSg,
                                       const float4* Sl, const unsigned* CSl,
                                       int c_lo, unsigned p_lo, bool staged) {
    int cx = cell_of(px), cy = cell_of(py), cz = cell_of(pz);
    unsigned long long best = 0xFFFFFFFFFFFFFFFFULL;
    {   // ---- r = 1 ----
        int x0 = max(cx - 1, 0), x1 = min(cx + 1, GR - 1);
        unsigned long long lb = 0xFFFFFFFFFFFFFFFFULL;
        for (int k = lane; k < 9; k += QL) {
            int z = cz + k / 3 - 1, y = cy + k % 3 - 1;
            if (z >= 0 && z < GR && y >= 0 && y < GR) {
                int rowbase = (z * GR + y) * GR;
                if (staged) {
                    unsigned s0 = CSl[rowbase + x0 - c_lo];
                    unsigned s1 = CSl[rowbase + x1 + 1 - c_lo];
                    for (unsigned u = s0; u < s1; ++u)
                        lb = u64min(lb, pack_key(px, py, pz, Sl[u - p_lo]));
                } else {
                    unsigned s0 = CSg[rowbase + x0];
                    unsigned s1 = CSg[rowbase + x1 + 1];
                    for (unsigned u = s0; u < s1; ++u)
                        lb = u64min(lb, pack_key(px, py, pz, Sg[u]));
                }
            }
        }
        best = lb;
        #pragma unroll
        for (int m = 1; m < QL; m <<= 1)
            best = u64min(best, (unsigned long long)__shfl_xor((long long)best, m, 64));
        bool covered = (cx - 1 <= 0) & (cx + 1 >= GR - 1) &
                       (cy - 1 <= 0) & (cy + 1 >= GR - 1) &
                       (cz - 1 <= 0) & (cz + 1 >= GR - 1);
        float blo = 1.0e30f;
        if (cx - 1 > 0)      blo = fminf(blo, px - (float)(cx - 1) * HCELL);
        if (cx + 1 < GR - 1) blo = fminf(blo, (float)(cx + 2) * HCELL - px);
        if (cy - 1 > 0)      blo = fminf(blo, py - (float)(cy - 1) * HCELL);
        if (cy + 1 < GR - 1) blo = fminf(blo, (float)(cy + 2) * HCELL - py);
        if (cz - 1 > 0)      blo = fminf(blo, pz - (float)(cz - 1) * HCELL);
        if (cz + 1 < GR - 1) blo = fminf(blo, (float)(cz + 2) * HCELL - pz);
        float bd2 = __uint_as_float((unsigned)(best >> 32));
        if (covered || (bd2 <= blo * blo)) return best;   // NaN -> expand
    }
    for (int r = 2; ; ++r) {   // ---- cold global path ----
        int w = 2 * r + 1;
        int nrows = w * w;
        int x0 = max(cx - r, 0), x1 = min(cx + r, GR - 1);
        unsigned long long lb = 0xFFFFFFFFFFFFFFFFULL;
        for (int k = lane; k < nrows; k += QL) {
            int z = cz + k / w - r, y = cy + k % w - r;
            if (z >= 0 && z < GR && y >= 0 && y < GR) {
                int rowbase = (z * GR + y) * GR;
                unsigned s0 = CSg[rowbase + x0];
                unsigned s1 = CSg[rowbase + x1 + 1];
                for (unsigned u = s0; u < s1; ++u)
                    lb = u64min(lb, pack_key(px, py, pz, Sg[u]));
            }
        }
        best = u64min(best, lb);
        #pragma unroll
        for (int m = 1; m < QL; m <<= 1)
            best = u64min(best, (unsigned long long)__shfl_xor((long long)best, m, 64));
        bool covered = (cx - r <= 0) & (cx + r >= GR - 1) &
                       (cy - r <= 0) & (cy + r >= GR - 1) &
                       (cz - r <= 0) & (cz + r >= GR - 1);
        if (covered) break;
        float blo = 1.0e30f;
        if (cx - r > 0)      blo = fminf(blo, px - (float)(cx - r) * HCELL);
        if (cx + r < GR - 1) blo = fminf(blo, (float)(cx + r + 1) * HCELL - px);
        if (cy - r > 0)      blo = fminf(blo, py - (float)(cy - r) * HCELL);
        if (cy + r < GR - 1) blo = fminf(blo, (float)(cy + r + 1) * HCELL - py);
        if (cz - r > 0)      blo = fminf(blo, pz - (float)(cz - r) * HCELL);
        if (cz + r < GR - 1) blo = fminf(blo, (float)(cz + r + 1) * HCELL - pz);
        float bd2 = __uint_as_float((unsigned)(best >> 32));
        if (bd2 <= blo * blo) break;
    }
    return best;
}

// Dispatch 2 (1024-thr blocks):
//   [0,128)    pred->gt query blocks (64 queries, LDS-staged gt window)
//   [128,316)  gt->pred query blocks (64 queries, LDS-staged pred window)
//   [316,356)  face scatter via global atomics (proven cheap)
__global__ __launch_bounds__(1024) void work_kernel(const float* __restrict__ pred,
                                                    const int* __restrict__ pf,
                                                    const float* __restrict__ gt,
                                                    const int* __restrict__ gf,
                                                    const float4* __restrict__ sortP,
                                                    const float4* __restrict__ sortG,
                                                    const unsigned* __restrict__ startP,
                                                    const unsigned* __restrict__ startG,
                                                    float* __restrict__ gtn,
                                                    float* __restrict__ pnn,
                                                    float* __restrict__ nsum,
                                                    float* __restrict__ deg,
                                                    int* __restrict__ nearestIdx,
                                                    float* __restrict__ accum) {
    __shared__ float4 lpts[CAPP];      // 73728 B
    __shared__ unsigned lcs[CWCAP];    // 5248 B
    __shared__ float qacc;
    __shared__ int s_info[4];          // c_lo, p_lo, np, +-cw
    int b = blockIdx.x, t = threadIdx.x;

    if (b < PQB + GQB) {
        bool is_pred = (b < PQB);
        const float4*   Q  = is_pred ? sortP  : sortG;
        const float4*   S  = is_pred ? sortG  : sortP;
        const unsigned* CS = is_pred ? startG : startP;
        int qbase = (is_pred ? b : (b - PQB)) * QPBLK;
        int nq = min(QPBLK, (is_pred ? NP : NG) - qbase);

        if (t == 0) {
            qacc = 0.0f;
            float4 qf = Q[qbase], ql = Q[qbase + nq - 1];
            int z_lo = cell_of(qf.z), z_hi = cell_of(ql.z);
            int c_lo  = max(z_lo - 1, 0) * (GR * GR);
            int c_end = min(z_hi + 2, GR) * (GR * GR);   // inclusive cstart idx
            int cw = c_end - c_lo + 1;
            unsigned p_lo = CS[c_lo], p_hi = CS[c_end];
            int np = (int)(p_hi - p_lo);
            bool ok = (cw <= CWCAP) && (np <= CAPP);
            s_info[0] = c_lo; s_info[1] = (int)p_lo; s_info[2] = np;
            s_info[3] = ok ? cw : -cw;
        }
        __syncthreads();
        int c_lo = s_info[0];
        unsigned p_lo = (unsigned)s_info[1];
        int np = s_info[2];
        int cw = s_info[3];
        bool staged = (cw > 0);
        if (staged) {
            for (int i = t; i < np; i += 1024) lpts[i] = S[p_lo + i];
            for (int i = t; i < cw; i += 1024) lcs[i]  = CS[c_lo + i];
        }
        __syncthreads();

        int lane = t & (QL - 1), group = t >> 4;     // group 0..63
        float r0 = 0.0f;
        if (group < nq) {
            int qid = qbase + group;
            float4 P = Q[qid];
            unsigned long long key = group_nn(lane, P.x, P.y, P.z, S, CS,
                                              lpts, lcs, c_lo, p_lo, staged);
            if (lane == 0) {
                r0 = __uint_as_float((unsigned)(key >> 32));
                if (is_pred)
                    nearestIdx[__float_as_int(P.w)] = (int)(unsigned)(key & 0xffffffffu);
            }
        }
        r0 = wave_sum(r0);
        if ((t & 63) == 0) atomicAdd(&qacc, r0);
        __syncthreads();
        if (t == 0) atomicAdd(&accum[is_pred ? 0 : 6], qacc);
    } else {
        int f = (b - PQB - GQB) * 1024 + t;
        if (f < NFG) {
            int i0 = gf[3*f], i1 = gf[3*f+1], i2 = gf[3*f+2];
            float ax = gt[3*i0], ay = gt[3*i0+1], az = gt[3*i0+2];
            float bx = gt[3*i1], by = gt[3*i1+1], bz = gt[3*i1+2];
            float cx = gt[3*i2], cy = gt[3*i2+1], cz = gt[3*i2+2];
            float ux = bx-ax, uy = by-ay, uz = bz-az;
            float wx = cx-ax, wy = cy-ay, wz = cz-az;
            float nx = uy*wz - uz*wy, ny = uz*wx - ux*wz, nz = ux*wy - uy*wx;
            atomicAdd(&gtn[3*i0+0], nx); atomicAdd(&gtn[3*i0+1], ny); atomicAdd(&gtn[3*i0+2], nz);
            atomicAdd(&gtn[3*i1+0], nx); atomicAdd(&gtn[3*i1+1], ny); atomicAdd(&gtn[3*i1+2], nz);
            atomicAdd(&gtn[3*i2+0], nx); atomicAdd(&gtn[3*i2+1], ny); atomicAdd(&gtn[3*i2+2], nz);
        } else if (f < NFG + NFP) {
            int u = f - NFG;
            int i0 = pf[3*u], i1 = pf[3*u+1], i2 = pf[3*u+2];
            float ax = pred[3*i0], ay = pred[3*i0+1], az = pred[3*i0+2];
            float bx = pred[3*i1], by = pred[3*i1+1], bz = pred[3*i1+2];
            float cx = pred[3*i2], cy = pred[3*i2+1], cz = pred[3*i2+2];
            float ux = bx-ax, uy = by-ay, uz = bz-az;
            float wx = cx-ax, wy = cy-ay, wz = cz-az;
            float nx = uy*wz - uz*wy, ny = uz*wx - ux*wz, nz = ux*wy - uy*wx;
            atomicAdd(&pnn[3*i0+0], nx); atomicAdd(&pnn[3*i0+1], ny); atomicAdd(&pnn[3*i0+2], nz);
            atomicAdd(&pnn[3*i1+0], nx); atomicAdd(&pnn[3*i1+1], ny); atomicAdd(&pnn[3*i1+2], nz);
            atomicAdd(&pnn[3*i2+0], nx); atomicAdd(&pnn[3*i2+1], ny); atomicAdd(&pnn[3*i2+2], nz);
            atomicAdd(&nsum[3*i0+0], bx+cx); atomicAdd(&nsum[3*i0+1], by+cy); atomicAdd(&nsum[3*i0+2], bz+cz);
            atomicAdd(&nsum[3*i1+0], cx+ax); atomicAdd(&nsum[3*i1+1], cy+ay); atomicAdd(&nsum[3*i1+2], cz+az);
            atomicAdd(&nsum[3*i2+0], ax+bx); atomicAdd(&nsum[3*i2+1], ay+by); atomicAdd(&nsum[3*i2+2], az+bz);
            atomicAdd(&deg[i0], 2.0f); atomicAdd(&deg[i1], 2.0f); atomicAdd(&deg[i2], 2.0f);
        }
    }
}

// Dispatch 3: fully-parallel per-vertex epilogue; last block (done-counter)
// computes the final scalar. (Proven structure.)
__global__ __launch_bounds__(256) void finish_kernel(const float* __restrict__ pred,
                                                     const float* __restrict__ relpos,
                                                     const int* __restrict__ label,
                                                     const float* __restrict__ pnn,
                                                     const float* __restrict__ gtn,
                                                     const float* __restrict__ nsum,
                                                     const float* __restrict__ deg,
                                                     const int* __restrict__ nearestIdx,
                                                     float* __restrict__ accum,
                                                     unsigned* __restrict__ done,
                                                     float* __restrict__ out) {
    int v = blockIdx.x * 256 + threadIdx.x;     // < 8192 exact
    float px = pred[3*v], py = pred[3*v+1], pz = pred[3*v+2];
    int nearest = nearestIdx[v];

    // normal consistency (normalize both accumulators on the fly)
    float ax = pnn[3*v], ay = pnn[3*v+1], az = pnn[3*v+2];
    float an = fmaxf(sqrtf(ax*ax + ay*ay + az*az), EPSF);
    float gx = gtn[3*nearest], gy = gtn[3*nearest+1], gz = gtn[3*nearest+2];
    float gn = fmaxf(sqrtf(gx*gx + gy*gy + gz*gz), EPSF);
    float nx = ax/an - gx/gn, ny = ay/an - gy/gn, nz = az/an - gz/gn;
    float sse = nx*nx + ny*ny + nz*nz;

    // laplacian
    float d = fmaxf(deg[v], 1.0f);
    float lx = nsum[3*v]/d - px, ly = nsum[3*v+1]/d - py, lz = nsum[3*v+2]/d - pz;
    float lapn = sqrtf(lx*lx + ly*ly + lz*lz);

    // grid-sample target (nearest, align_corners=True, zeros padding)
    int ix = (int)rintf(px * 95.0f), iy = (int)rintf(py * 95.0f), iz = (int)rintf(pz * 95.0f);
    bool inb = (ix >= 0) & (ix < 96) & (iy >= 0) & (iy < 96) & (iz >= 0) & (iz < 96);
    int ixc = min(max(ix, 0), 95), iyc = min(max(iy, 0), 95), izc = min(max(iz, 0), 95);
    bool pos = inb && (label[(izc*96 + iyc)*96 + ixc] == 1);

    float p = fminf(fmaxf(relpos[v], EPSF), 1.0f - EPSF);
    float om = 1.0f - p;
    float pcnt = 0.0f, sx = 0.0f, sy = 0.0f;
    if (pos) { pcnt = 1.0f; sx = om*om*logf(p); }
    else     { sy = p*p*logf(om); }

    float r1 = wave_sum(sse), r2 = wave_sum(lapn), r3 = wave_sum(pcnt);
    float r4 = wave_sum(sx),  r5 = wave_sum(sy);
    __shared__ float bsum[5];
    __shared__ bool isLast;
    if (threadIdx.x < 5) bsum[threadIdx.x] = 0.0f;
    __syncthreads();
    if ((threadIdx.x & 63) == 0) {
        atomicAdd(&bsum[0], r1); atomicAdd(&bsum[1], r2); atomicAdd(&bsum[2], r3);
        atomicAdd(&bsum[3], r4); atomicAdd(&bsum[4], r5);
    }
    __syncthreads();
    if (threadIdx.x == 0) {
        atomicAdd(&accum[1], bsum[0]); atomicAdd(&accum[2], bsum[1]);
        atomicAdd(&accum[3], bsum[2]); atomicAdd(&accum[4], bsum[3]);
        atomicAdd(&accum[5], bsum[4]);
        __threadfence();                         // publish before done-count
        unsigned prev = atomicAdd(done, 1u);
        isLast = (prev == FIN_BLOCKS - 1);
    }
    __syncthreads();
    if (isLast && threadIdx.x == 0) {
        __threadfence();
        float sum_row = __hip_atomic_load(&accum[0], __ATOMIC_RELAXED, __HIP_MEMORY_SCOPE_AGENT);
        float sse_t   = __hip_atomic_load(&accum[1], __ATOMIC_RELAXED, __HIP_MEMORY_SCOPE_AGENT);
        float lap_t   = __hip_atomic_load(&accum[2], __ATOMIC_RELAXED, __HIP_MEMORY_SCOPE_AGENT);
        float pc      = __hip_atomic_load(&accum[3], __ATOMIC_RELAXED, __HIP_MEMORY_SCOPE_AGENT);
        float SX      = __hip_atomic_load(&accum[4], __ATOMIC_RELAXED, __HIP_MEMORY_SCOPE_AGENT);
        float SY      = __hip_atomic_load(&accum[5], __ATOMIC_RELAXED, __HIP_MEMORY_SCOPE_AGENT);
        float sum_col = __hip_atomic_load(&accum[6], __ATOMIC_RELAXED, __HIP_MEMORY_SCOPE_AGENT);
        float tot = (float)NP;
        float alpha = (tot - pc) / (tot + EPSF);
        float spatial = (-alpha * SX - (1.0f - alpha) * SY) / (tot + EPSF);
        float distance = sum_row / (float)NP + sum_col / (float)NG;
        float normal = sse_t / (float)(NP * 3);
        float lapm = lap_t / (float)NP;
        out[0] = spatial + 1.0f * distance + 0.01f * normal + 0.1f * lapm;
    }
}

extern "C" void kernel_launch(void* const* d_in, const int* in_sizes, int n_in,
                              void* d_out, int out_size, void* d_ws, size_t ws_size,
                              hipStream_t stream) {
    const float* pred   = (const float*)d_in[0];   // [8192,3]
    const float* relpos = (const float*)d_in[1];   // [8192]
    const float* gt     = (const float*)d_in[2];   // [12000,3]
    const int*   pfaces = (const int*)d_in[3];     // [16384,3]
    const int*   gfaces = (const int*)d_in[4];     // [24000,3]
    const int*   label  = (const int*)d_in[5];     // [1,1,96,96,96]
    float* out = (float*)d_out;

    char* ws = (char*)d_ws;
    unsigned* startP  = (unsigned*)(ws + OFF_STARTP);
    unsigned* startG  = (unsigned*)(ws + OFF_STARTG);
    float4*   sortP   = (float4*)(ws + OFF_SORTP);
    float4*   sortG   = (float4*)(ws + OFF_SORTG);
    float*    gtn     = (float*)(ws + OFF_GTN);
    float*    pnn     = (float*)(ws + OFF_PNN);
    float*    nsum    = (float*)(ws + OFF_NSUM);
    float*    deg     = (float*)(ws + OFF_DEG);
    int*      nearest = (int*)(ws + OFF_NEAR);
    float*    accum   = (float*)(ws + OFF_ACCUM);
    unsigned* done    = (unsigned*)(ws + OFF_DONE);

    // d1: grid build (b0,b1) || zero accumulation region (b2..)
    hipLaunchKernelGGL(build_kernel, dim3(D1_BLOCKS), dim3(1024), 0, stream,
                       pred, gt, startP, startG, sortP, sortG,
                       (float*)(ws + OFF_GTN));
    // d2: LDS-windowed group NN (both dirs) || face atomic scatter
    hipLaunchKernelGGL(work_kernel, dim3(D2_BLOCKS), dim3(1024), 0, stream,
                       pred, pfaces, gt, gfaces, sortP, sortG, startP, startG,
                       gtn, pnn, nsum, deg, nearest, accum);
    // d3: per-vertex epilogue + last-block combine
    hipLaunchKernelGGL(finish_kernel, dim3(FIN_BLOCKS), dim3(256), 0, stream,
                       pred, relpos, label, pnn, gtn, nsum, deg, nearest,
                       accum, done, out);
}

// Round 7
// 131.167 us; speedup vs baseline: 1.8746x; 1.0077x over previous
//
#include <hip/hip_runtime.h>
#include <math.h>

// Problem constants (fixed by setup_inputs)
#define NP 8192      // pred vertices
#define NG 12000     // gt vertices
#define NFP 16384    // pred faces
#define NFG 24000    // gt faces
#define EPSF 1e-6f

// uniform grid for NN: 16^3 cells over [0,1]^3, ~3 gt / ~2 pred per cell
#define GR 16
#define NC (GR*GR*GR)        // 4096
#define HCELL 0.0625f        // 1/16, exact power of two
#define QL 16                // lanes cooperating per NN query (proven best)

// D1 (1024-thr): b0 pred build, b1 gt build, b2.. face scatter
#define FB ((NFG + NFP + 1023) / 1024)            // 40
#define D1_BLOCKS (2 + FB)                        // 42

// D2 (1024-thr): query-only blocks, 64 queries each, LDS-staged window
#define QPBLK 64
#define PQB (NP / QPBLK)                          // 128
#define GQB ((NG + QPBLK - 1) / QPBLK)            // 188 (last block 32 queries)
#define D2_BLOCKS (PQB + GQB)                     // 316

// LDS staging capacities (overflow -> correct global fallback)
#define CAPP  4608           // points (float4) = 73728 B
#define CWCAP 1312           // cstart window entries (covers 5 z-slabs + 1)

// D3: per-vertex epilogue + combine
#define FIN_BLOCKS (NP / 256)                     // 32

// ---- workspace layout (bytes) ----
static constexpr size_t OFF_STARTP = 0;        // (NC+1) u32, [NC]=NP
static constexpr size_t OFF_STARTG = 16640;    // (NC+1) u32, [NC]=NG
static constexpr size_t OFF_SORTP  = 33280;    // 8192  float4 (x,y,z,idx-bits)
static constexpr size_t OFF_SORTG  = 164352;   // 12000 float4
static constexpr size_t OFF_GTN    = 356352;   // NG*3 f32 gt normal accum   <- memset region start
static constexpr size_t OFF_PNN    = 500352;   // NP*3 f32 pred normal accum
static constexpr size_t OFF_NSUM   = 598656;   // NP*3 f32 laplacian neighbor sum
static constexpr size_t OFF_DEG    = 696960;   // NP   f32 laplacian degree
static constexpr size_t OFF_NEAR   = 729728;   // NP   i32 nearest gt (original idx)
static constexpr size_t OFF_ACCUM  = 762496;   // 8 f32 global accumulators
static constexpr size_t OFF_DONE   = 762528;   // 1 u32 done-counter          <- memset region end
static constexpr size_t ZERO_BYTES = OFF_DONE + 4 - OFF_GTN;   // 406180

__device__ __forceinline__ int cell_of(float x) {
    int c = (int)(x * (float)GR);
    return min(max(c, 0), GR - 1);
}

// One block builds one point set: histogram -> shuffle scan -> start[] ->
// scatter into cell-sorted order via LDS cursor table. (Proven cheap.)
__device__ __forceinline__ void build_cells(const float* __restrict__ pts, int n,
                                            unsigned* __restrict__ start,
                                            float4* __restrict__ sorted,
                                            unsigned* h, unsigned* wsum) {
    int t = threadIdx.x;                 // 0..1023
    int lane = t & 63, wid = t >> 6;     // 16 waves
    for (int i = t; i < NC; i += 1024) h[i] = 0u;
    __syncthreads();
    for (int i = t; i < n; i += 1024) {
        int c = (cell_of(pts[3*i+2]) * GR + cell_of(pts[3*i+1])) * GR + cell_of(pts[3*i]);
        atomicAdd(&h[c], 1u);
    }
    __syncthreads();
    unsigned a0 = h[4*t], a1 = h[4*t+1], a2 = h[4*t+2], a3 = h[4*t+3];
    unsigned tsum = a0 + a1 + a2 + a3;
    unsigned x = tsum;
    #pragma unroll
    for (int off = 1; off < 64; off <<= 1) {
        unsigned y = __shfl_up(x, off, 64);
        if (lane >= off) x += y;
    }
    if (lane == 63) wsum[wid] = x;       // wave totals
    __syncthreads();
    if (t < 16) {                        // scan 16 wave totals inside wave 0
        unsigned w = wsum[t];
        #pragma unroll
        for (int off = 1; off < 16; off <<= 1) {
            unsigned y = __shfl_up(w, off, 64);
            if (t >= off) w += y;
        }
        wsum[t] = w;                     // inclusive
    }
    __syncthreads();
    unsigned base = (wid ? wsum[wid-1] : 0u) + (x - tsum);  // exclusive prefix
    unsigned e0 = base, e1 = base + a0, e2 = base + a0 + a1, e3 = base + a0 + a1 + a2;
    start[4*t] = e0; start[4*t+1] = e1; start[4*t+2] = e2; start[4*t+3] = e3;
    h[4*t] = e0; h[4*t+1] = e1; h[4*t+2] = e2; h[4*t+3] = e3;  // reuse as cursor
    __syncthreads();
    for (int i = t; i < n; i += 1024) {
        float px = pts[3*i], py = pts[3*i+1], pz = pts[3*i+2];
        int c = (cell_of(pz) * GR + cell_of(py)) * GR + cell_of(px);
        unsigned pos = atomicAdd(&h[c], 1u);
        sorted[pos] = make_float4(px, py, pz, __int_as_float(i));
    }
    if (t == 0) start[NC] = (unsigned)n;   // end sentinel
}

// Dispatch 1: grid build (b0,b1) || face atomic scatter (b2..).
// Faces depend only on raw inputs + the memset-zeroed accumulators, so they
// run HERE, not beside the latency-sensitive queries (isolates TCC atomic
// traffic from query loads -- the suspected 40us interference).
__global__ __launch_bounds__(1024) void build_face_kernel(const float* __restrict__ pred,
                                                          const float* __restrict__ gt,
                                                          const int* __restrict__ pf,
                                                          const int* __restrict__ gf,
                                                          unsigned* __restrict__ startP,
                                                          unsigned* __restrict__ startG,
                                                          float4* __restrict__ sortP,
                                                          float4* __restrict__ sortG,
                                                          float* __restrict__ gtn,
                                                          float* __restrict__ pnn,
                                                          float* __restrict__ nsum,
                                                          float* __restrict__ deg) {
    __shared__ unsigned h[NC];
    __shared__ unsigned wsum[16];
    int b = blockIdx.x, t = threadIdx.x;
    if (b == 0) {
        build_cells(pred, NP, startP, sortP, h, wsum);
    } else if (b == 1) {
        build_cells(gt, NG, startG, sortG, h, wsum);
    } else {
        int f = (b - 2) * 1024 + t;
        if (f < NFG) {
            int i0 = gf[3*f], i1 = gf[3*f+1], i2 = gf[3*f+2];
            float ax = gt[3*i0], ay = gt[3*i0+1], az = gt[3*i0+2];
            float bx = gt[3*i1], by = gt[3*i1+1], bz = gt[3*i1+2];
            float cx = gt[3*i2], cy = gt[3*i2+1], cz = gt[3*i2+2];
            float ux = bx-ax, uy = by-ay, uz = bz-az;
            float wx = cx-ax, wy = cy-ay, wz = cz-az;
            float nx = uy*wz - uz*wy, ny = uz*wx - ux*wz, nz = ux*wy - uy*wx;
            atomicAdd(&gtn[3*i0+0], nx); atomicAdd(&gtn[3*i0+1], ny); atomicAdd(&gtn[3*i0+2], nz);
            atomicAdd(&gtn[3*i1+0], nx); atomicAdd(&gtn[3*i1+1], ny); atomicAdd(&gtn[3*i1+2], nz);
            atomicAdd(&gtn[3*i2+0], nx); atomicAdd(&gtn[3*i2+1], ny); atomicAdd(&gtn[3*i2+2], nz);
        } else if (f < NFG + NFP) {
            int u = f - NFG;
            int i0 = pf[3*u], i1 = pf[3*u+1], i2 = pf[3*u+2];
            float ax = pred[3*i0], ay = pred[3*i0+1], az = pred[3*i0+2];
            float bx = pred[3*i1], by = pred[3*i1+1], bz = pred[3*i1+2];
            float cx = pred[3*i2], cy = pred[3*i2+1], cz = pred[3*i2+2];
            float ux = bx-ax, uy = by-ay, uz = bz-az;
            float wx = cx-ax, wy = cy-ay, wz = cz-az;
            float nx = uy*wz - uz*wy, ny = uz*wx - ux*wz, nz = ux*wy - uy*wx;
            atomicAdd(&pnn[3*i0+0], nx); atomicAdd(&pnn[3*i0+1], ny); atomicAdd(&pnn[3*i0+2], nz);
            atomicAdd(&pnn[3*i1+0], nx); atomicAdd(&pnn[3*i1+1], ny); atomicAdd(&pnn[3*i1+2], nz);
            atomicAdd(&pnn[3*i2+0], nx); atomicAdd(&pnn[3*i2+1], ny); atomicAdd(&pnn[3*i2+2], nz);
            atomicAdd(&nsum[3*i0+0], bx+cx); atomicAdd(&nsum[3*i0+1], by+cy); atomicAdd(&nsum[3*i0+2], bz+cz);
            atomicAdd(&nsum[3*i1+0], cx+ax); atomicAdd(&nsum[3*i1+1], cy+ay); atomicAdd(&nsum[3*i1+2], cz+az);
            atomicAdd(&nsum[3*i2+0], ax+bx); atomicAdd(&nsum[3*i2+1], ay+by); atomicAdd(&nsum[3*i2+2], az+bz);
            atomicAdd(&deg[i0], 2.0f); atomicAdd(&deg[i1], 2.0f); atomicAdd(&deg[i2], 2.0f);
        }
    }
}

__device__ __forceinline__ float wave_sum(float x) {
    #pragma unroll
    for (int o = 32; o > 0; o >>= 1) x += __shfl_down(x, o, 64);
    return x;
}

__device__ __forceinline__ unsigned long long u64min(unsigned long long a,
                                                     unsigned long long b) {
    return a < b ? a : b;
}

__device__ __forceinline__ unsigned long long pack_key(float px, float py, float pz,
                                                       float4 q) {
    float ddx = px - q.x, ddy = py - q.y, ddz = pz - q.z;
    float d2 = fmaf(ddx, ddx, fmaf(ddy, ddy, ddz*ddz));
    return ((unsigned long long)__float_as_uint(d2) << 32) |
           (unsigned)__float_as_int(q.w);
}

// 16-lane group NN, r=1 from the LDS-staged window. Lane mapping is now
// CELL-granular (27 cells over 16 lanes) instead of row-granular (9 rows
// over 9 of 16 lanes -- 44% idle). Key-min is commutative, so the remap is
// bit-identical. r>=2 (~1e-4 of queries) and unstaged blocks use global.
__device__ unsigned long long group_nn(int lane, float px, float py, float pz,
                                       const float4* __restrict__ Sg,
                                       const unsigned* __restrict__ CSg,
                                       const float4* Sl, const unsigned* CSl,
                                       int c_lo, unsigned p_lo, bool staged) {
    int cx = cell_of(px), cy = cell_of(py), cz = cell_of(pz);
    unsigned long long best = 0xFFFFFFFFFFFFFFFFULL;
    {   // ---- r = 1: 27 cells across 16 lanes ----
        unsigned long long lb = 0xFFFFFFFFFFFFFFFFULL;
        for (int k = lane; k < 27; k += QL) {
            int z = cz + k / 9 - 1, y = cy + (k % 9) / 3 - 1, x = cx + k % 3 - 1;
            if (((unsigned)z < GR) & ((unsigned)y < GR) & ((unsigned)x < GR)) {
                int c = (z * GR + y) * GR + x;
                if (staged) {
                    unsigned s0 = CSl[c - c_lo];
                    unsigned s1 = CSl[c + 1 - c_lo];
                    for (unsigned u = s0; u < s1; ++u)
                        lb = u64min(lb, pack_key(px, py, pz, Sl[u - p_lo]));
                } else {
                    unsigned s0 = CSg[c];
                    unsigned s1 = CSg[c + 1];
                    for (unsigned u = s0; u < s1; ++u)
                        lb = u64min(lb, pack_key(px, py, pz, Sg[u]));
                }
            }
        }
        best = lb;
        #pragma unroll
        for (int m = 1; m < QL; m <<= 1)
            best = u64min(best, (unsigned long long)__shfl_xor((long long)best, m, 64));
        bool covered = (cx - 1 <= 0) & (cx + 1 >= GR - 1) &
                       (cy - 1 <= 0) & (cy + 1 >= GR - 1) &
                       (cz - 1 <= 0) & (cz + 1 >= GR - 1);
        float blo = 1.0e30f;
        if (cx - 1 > 0)      blo = fminf(blo, px - (float)(cx - 1) * HCELL);
        if (cx + 1 < GR - 1) blo = fminf(blo, (float)(cx + 2) * HCELL - px);
        if (cy - 1 > 0)      blo = fminf(blo, py - (float)(cy - 1) * HCELL);
        if (cy + 1 < GR - 1) blo = fminf(blo, (float)(cy + 2) * HCELL - py);
        if (cz - 1 > 0)      blo = fminf(blo, pz - (float)(cz - 1) * HCELL);
        if (cz + 1 < GR - 1) blo = fminf(blo, (float)(cz + 2) * HCELL - pz);
        float bd2 = __uint_as_float((unsigned)(best >> 32));
        if (covered || (bd2 <= blo * blo)) return best;   // NaN -> expand
    }
    for (int r = 2; ; ++r) {   // ---- cold global path ----
        int w = 2 * r + 1;
        int nrows = w * w;
        int x0 = max(cx - r, 0), x1 = min(cx + r, GR - 1);
        unsigned long long lb = 0xFFFFFFFFFFFFFFFFULL;
        for (int k = lane; k < nrows; k += QL) {
            int z = cz + k / w - r, y = cy + k % w - r;
            if (z >= 0 && z < GR && y >= 0 && y < GR) {
                int rowbase = (z * GR + y) * GR;
                unsigned s0 = CSg[rowbase + x0];
                unsigned s1 = CSg[rowbase + x1 + 1];
                for (unsigned u = s0; u < s1; ++u)
                    lb = u64min(lb, pack_key(px, py, pz, Sg[u]));
            }
        }
        best = u64min(best, lb);
        #pragma unroll
        for (int m = 1; m < QL; m <<= 1)
            best = u64min(best, (unsigned long long)__shfl_xor((long long)best, m, 64));
        bool covered = (cx - r <= 0) & (cx + r >= GR - 1) &
                       (cy - r <= 0) & (cy + r >= GR - 1) &
                       (cz - r <= 0) & (cz + r >= GR - 1);
        if (covered) break;
        float blo = 1.0e30f;
        if (cx - r > 0)      blo = fminf(blo, px - (float)(cx - r) * HCELL);
        if (cx + r < GR - 1) blo = fminf(blo, (float)(cx + r + 1) * HCELL - px);
        if (cy - r > 0)      blo = fminf(blo, py - (float)(cy - r) * HCELL);
        if (cy + r < GR - 1) blo = fminf(blo, (float)(cy + r + 1) * HCELL - py);
        if (cz - r > 0)      blo = fminf(blo, pz - (float)(cz - r) * HCELL);
        if (cz + r < GR - 1) blo = fminf(blo, (float)(cz + r + 1) * HCELL - pz);
        float bd2 = __uint_as_float((unsigned)(best >> 32));
        if (bd2 <= blo * blo) break;
    }
    return best;
}

// Dispatch 2 (1024-thr blocks, QUERIES ONLY -- no face atomics in flight):
//   [0,128)    pred->gt query blocks (64 queries, LDS-staged gt window)
//   [128,316)  gt->pred query blocks (64 queries, LDS-staged pred window)
__global__ __launch_bounds__(1024) void query_kernel(const float4* __restrict__ sortP,
                                                     const float4* __restrict__ sortG,
                                                     const unsigned* __restrict__ startP,
                                                     const unsigned* __restrict__ startG,
                                                     int* __restrict__ nearestIdx,
                                                     float* __restrict__ accum) {
    __shared__ float4 lpts[CAPP];      // 73728 B
    __shared__ unsigned lcs[CWCAP];    // 5248 B
    __shared__ float qacc;
    __shared__ int s_info[4];          // c_lo, p_lo, np, +-cw
    int b = blockIdx.x, t = threadIdx.x;

    bool is_pred = (b < PQB);
    const float4*   Q  = is_pred ? sortP  : sortG;
    const float4*   S  = is_pred ? sortG  : sortP;
    const unsigned* CS = is_pred ? startG : startP;
    int qbase = (is_pred ? b : (b - PQB)) * QPBLK;
    int nq = min(QPBLK, (is_pred ? NP : NG) - qbase);

    if (t == 0) {
        qacc = 0.0f;
        float4 qf = Q[qbase], ql = Q[qbase + nq - 1];
        int z_lo = cell_of(qf.z), z_hi = cell_of(ql.z);
        int c_lo  = max(z_lo - 1, 0) * (GR * GR);
        int c_end = min(z_hi + 2, GR) * (GR * GR);   // inclusive cstart idx
        int cw = c_end - c_lo + 1;
        unsigned p_lo = CS[c_lo], p_hi = CS[c_end];
        int np = (int)(p_hi - p_lo);
        bool ok = (cw <= CWCAP) && (np <= CAPP);
        s_info[0] = c_lo; s_info[1] = (int)p_lo; s_info[2] = np;
        s_info[3] = ok ? cw : -cw;
    }
    __syncthreads();
    int c_lo = s_info[0];
    unsigned p_lo = (unsigned)s_info[1];
    int np = s_info[2];
    int cw = s_info[3];
    bool staged = (cw > 0);
    if (staged) {
        for (int i = t; i < np; i += 1024) lpts[i] = S[p_lo + i];
        for (int i = t; i < cw; i += 1024) lcs[i]  = CS[c_lo + i];
    }
    __syncthreads();

    int lane = t & (QL - 1), group = t >> 4;     // group 0..63
    float r0 = 0.0f;
    if (group < nq) {
        int qid = qbase + group;
        float4 P = Q[qid];
        unsigned long long key = group_nn(lane, P.x, P.y, P.z, S, CS,
                                          lpts, lcs, c_lo, p_lo, staged);
        if (lane == 0) {
            r0 = __uint_as_float((unsigned)(key >> 32));
            if (is_pred)
                nearestIdx[__float_as_int(P.w)] = (int)(unsigned)(key & 0xffffffffu);
        }
    }
    r0 = wave_sum(r0);
    if ((t & 63) == 0) atomicAdd(&qacc, r0);
    __syncthreads();
    if (t == 0) atomicAdd(&accum[is_pred ? 0 : 6], qacc);
}

// Dispatch 3: fully-parallel per-vertex epilogue; last block (done-counter)
// computes the final scalar. (Proven structure.)
__global__ __launch_bounds__(256) void finish_kernel(const float* __restrict__ pred,
                                                     const float* __restrict__ relpos,
                                                     const int* __restrict__ label,
                                                     const float* __restrict__ pnn,
                                                     const float* __restrict__ gtn,
                                                     const float* __restrict__ nsum,
                                                     const float* __restrict__ deg,
                                                     const int* __restrict__ nearestIdx,
                                                     float* __restrict__ accum,
                                                     unsigned* __restrict__ done,
                                                     float* __restrict__ out) {
    int v = blockIdx.x * 256 + threadIdx.x;     // < 8192 exact
    float px = pred[3*v], py = pred[3*v+1], pz = pred[3*v+2];
    int nearest = nearestIdx[v];

    // normal consistency (normalize both accumulators on the fly)
    float ax = pnn[3*v], ay = pnn[3*v+1], az = pnn[3*v+2];
    float an = fmaxf(sqrtf(ax*ax + ay*ay + az*az), EPSF);
    float gx = gtn[3*nearest], gy = gtn[3*nearest+1], gz = gtn[3*nearest+2];
    float gn = fmaxf(sqrtf(gx*gx + gy*gy + gz*gz), EPSF);
    float nx = ax/an - gx/gn, ny = ay/an - gy/gn, nz = az/an - gz/gn;
    float sse = nx*nx + ny*ny + nz*nz;

    // laplacian
    float d = fmaxf(deg[v], 1.0f);
    float lx = nsum[3*v]/d - px, ly = nsum[3*v+1]/d - py, lz = nsum[3*v+2]/d - pz;
    float lapn = sqrtf(lx*lx + ly*ly + lz*lz);

    // grid-sample target (nearest, align_corners=True, zeros padding)
    int ix = (int)rintf(px * 95.0f), iy = (int)rintf(py * 95.0f), iz = (int)rintf(pz * 95.0f);
    bool inb = (ix >= 0) & (ix < 96) & (iy >= 0) & (iy < 96) & (iz >= 0) & (iz < 96);
    int ixc = min(max(ix, 0), 95), iyc = min(max(iy, 0), 95), izc = min(max(iz, 0), 95);
    bool pos = inb && (label[(izc*96 + iyc)*96 + ixc] == 1);

    float p = fminf(fmaxf(relpos[v], EPSF), 1.0f - EPSF);
    float om = 1.0f - p;
    float pcnt = 0.0f, sx = 0.0f, sy = 0.0f;
    if (pos) { pcnt = 1.0f; sx = om*om*logf(p); }
    else     { sy = p*p*logf(om); }

    float r1 = wave_sum(sse), r2 = wave_sum(lapn), r3 = wave_sum(pcnt);
    float r4 = wave_sum(sx),  r5 = wave_sum(sy);
    __shared__ float bsum[5];
    __shared__ bool isLast;
    if (threadIdx.x < 5) bsum[threadIdx.x] = 0.0f;
    __syncthreads();
    if ((threadIdx.x & 63) == 0) {
        atomicAdd(&bsum[0], r1); atomicAdd(&bsum[1], r2); atomicAdd(&bsum[2], r3);
        atomicAdd(&bsum[3], r4); atomicAdd(&bsum[4], r5);
    }
    __syncthreads();
    if (threadIdx.x == 0) {
        atomicAdd(&accum[1], bsum[0]); atomicAdd(&accum[2], bsum[1]);
        atomicAdd(&accum[3], bsum[2]); atomicAdd(&accum[4], bsum[3]);
        atomicAdd(&accum[5], bsum[4]);
        __threadfence();                         // publish before done-count
        unsigned prev = atomicAdd(done, 1u);
        isLast = (prev == FIN_BLOCKS - 1);
    }
    __syncthreads();
    if (isLast && threadIdx.x == 0) {
        __threadfence();
        float sum_row = __hip_atomic_load(&accum[0], __ATOMIC_RELAXED, __HIP_MEMORY_SCOPE_AGENT);
        float sse_t   = __hip_atomic_load(&accum[1], __ATOMIC_RELAXED, __HIP_MEMORY_SCOPE_AGENT);
        float lap_t   = __hip_atomic_load(&accum[2], __ATOMIC_RELAXED, __HIP_MEMORY_SCOPE_AGENT);
        float pc      = __hip_atomic_load(&accum[3], __ATOMIC_RELAXED, __HIP_MEMORY_SCOPE_AGENT);
        float SX      = __hip_atomic_load(&accum[4], __ATOMIC_RELAXED, __HIP_MEMORY_SCOPE_AGENT);
        float SY      = __hip_atomic_load(&accum[5], __ATOMIC_RELAXED, __HIP_MEMORY_SCOPE_AGENT);
        float sum_col = __hip_atomic_load(&accum[6], __ATOMIC_RELAXED, __HIP_MEMORY_SCOPE_AGENT);
        float tot = (float)NP;
        float alpha = (tot - pc) / (tot + EPSF);
        float spatial = (-alpha * SX - (1.0f - alpha) * SY) / (tot + EPSF);
        float distance = sum_row / (float)NP + sum_col / (float)NG;
        float normal = sse_t / (float)(NP * 3);
        float lapm = lap_t / (float)NP;
        out[0] = spatial + 1.0f * distance + 0.01f * normal + 0.1f * lapm;
    }
}

extern "C" void kernel_launch(void* const* d_in, const int* in_sizes, int n_in,
                              void* d_out, int out_size, void* d_ws, size_t ws_size,
                              hipStream_t stream) {
    const float* pred   = (const float*)d_in[0];   // [8192,3]
    const float* relpos = (const float*)d_in[1];   // [8192]
    const float* gt     = (const float*)d_in[2];   // [12000,3]
    const int*   pfaces = (const int*)d_in[3];     // [16384,3]
    const int*   gfaces = (const int*)d_in[4];     // [24000,3]
    const int*   label  = (const int*)d_in[5];     // [1,1,96,96,96]
    float* out = (float*)d_out;

    char* ws = (char*)d_ws;
    unsigned* startP  = (unsigned*)(ws + OFF_STARTP);
    unsigned* startG  = (unsigned*)(ws + OFF_STARTG);
    float4*   sortP   = (float4*)(ws + OFF_SORTP);
    float4*   sortG   = (float4*)(ws + OFF_SORTG);
    float*    gtn     = (float*)(ws + OFF_GTN);
    float*    pnn     = (float*)(ws + OFF_PNN);
    float*    nsum    = (float*)(ws + OFF_NSUM);
    float*    deg     = (float*)(ws + OFF_DEG);
    int*      nearest = (int*)(ws + OFF_NEAR);
    float*    accum   = (float*)(ws + OFF_ACCUM);
    unsigned* done    = (unsigned*)(ws + OFF_DONE);

    // d0: zero accumulators (stream-ordered, graph-capturable)
    hipMemsetAsync(ws + OFF_GTN, 0, ZERO_BYTES, stream);
    // d1: grid build (b0,b1) || face atomic scatter (b2..)
    hipLaunchKernelGGL(build_face_kernel, dim3(D1_BLOCKS), dim3(1024), 0, stream,
                       pred, gt, pfaces, gfaces, startP, startG, sortP, sortG,
                       gtn, pnn, nsum, deg);
    // d2: LDS-windowed group NN, queries ONLY
    hipLaunchKernelGGL(query_kernel, dim3(D2_BLOCKS), dim3(1024), 0, stream,
                       sortP, sortG, startP, startG, nearest, accum);
    // d3: per-vertex epilogue + last-block combine
    hipLaunchKernelGGL(finish_kernel, dim3(FIN_BLOCKS), dim3(256), 0, stream,
                       pred, relpos, label, pnn, gtn, nsum, deg, nearest,
                       accum, done, out);
}